// Round 4
// baseline (1154.988 us; speedup 1.0000x reference)
//
#include <hip/hip_runtime.h>
#include <hip/hip_bf16.h>

typedef unsigned int   u32;
typedef unsigned short u16;
typedef _Float16       f16;
typedef __attribute__((ext_vector_type(2))) _Float16 f16x2;
typedef __attribute__((ext_vector_type(8))) _Float16 f16x8;
typedef __attribute__((ext_vector_type(4))) float    f32x4;
typedef __attribute__((ext_vector_type(2))) float    f32x2;

#define T_STEPS 512
#define BATCH   256
#define O_IN    720
#define KPAD    736      // 720 padded to mult of 32 (zero pad in wxt)
#define HID     128
#define G4      512      // 4*HID
// d_out layout (floats): am[512] | std[2] | value[256] | hT[32768] | cT[32768]
#define OUT_STD 512
#define OUT_VAL 514
#define OUT_HT  770
#define OUT_CT  33538

// ws layout (bytes); requires ws_size >= ~135 MB
// xwf: fragment-native xW+bias, f16. Per (s, b0): 32 frags x 64 lanes x 4 halves = 16KB.
// byte offset of (s, b0, f, lane): ((s*16 + b0)*32 + f)*512 + lane*8
static const unsigned long long XW_OFF  = 0ull;          // 134217728 B
static const unsigned long long WXT_OFF = 134217728ull;  // f16 [512][736] = 753664 B

__device__ inline float exp2fast(float x){
#if __has_builtin(__builtin_amdgcn_exp2f)
  return __builtin_amdgcn_exp2f(x);
#else
  return exp2f(x);
#endif
}
__device__ inline float sigf(float x){ return 1.0f / (1.0f + exp2fast(-1.44269504f * x)); }
__device__ inline float tanhfast(float x){ return 2.0f / (1.0f + exp2fast(-2.88539008f * x)) - 1.0f; }

__device__ inline u32 pkf16(float a, float b){
  f16x2 p; p[0] = (f16)a; p[1] = (f16)b; return __builtin_bit_cast(u32, p);
}
__device__ inline float lo16f(u32 u){ return (float)__builtin_bit_cast(f16, (u16)(u & 0xffffu)); }
__device__ inline float hi16f(u32 u){ return (float)__builtin_bit_cast(f16, (u16)(u >> 16)); }

// ---------------- K0: Wx (720,512) f32 -> Wx^T f16 [512][736] zero-padded ----------------
__global__ void k_pack_wxt(const float* __restrict__ Wx, u16* __restrict__ wxt){
  const int n = blockIdx.x;               // 512 blocks
  for (int k = threadIdx.x; k < KPAD; k += 256){
    float v = (k < O_IN) ? Wx[(size_t)k * G4 + n] : 0.f;
    wxt[(size_t)n * KPAD + k] = __builtin_bit_cast(u16, (f16)v);
  }
}

// ---------------- K1: xW = x @ Wx  (fp16 MFMA, LDS-free) + bias, frag-native epilogue -----
// grid 2048: WG tile 256x128 (4 waves of 64x128), K = 22*32 full + 16 tail.
__global__ __launch_bounds__(256, 2) void k_gemm(const float* __restrict__ x,
                                                 const u16* __restrict__ wxt,
                                                 const float* __restrict__ bvec,
                                                 u16* __restrict__ xwf)
{
  const int l  = threadIdx.x & 63;
  const int w  = threadIdx.x >> 6;
  const int lr = l & 15;        // A row / B col / D col
  const int lk = l >> 4;        // k-group (8 k each), lk in [0,4)
  // XCD-chunked swizzle (bijective: 2048 = 8*256)
  const u32 L  = (blockIdx.x & 7u) * 256u + (blockIdx.x >> 3);
  const u32 mb = L >> 2, nb = L & 3u;     // mb = s (timestep), full 256 batch rows per mb
  const u32 M0 = mb * 256u + (u32)w * 64u;
  const u32 N0 = nb * 128u;

  const float* ax[4];
  const u16*   bx[8];
#pragma unroll
  for (int mf = 0; mf < 4; ++mf)
    ax[mf] = x + (unsigned long long)(M0 + mf*16 + lr) * O_IN + lk*8;
#pragma unroll
  for (int nf = 0; nf < 8; ++nf)
    bx[nf] = wxt + (unsigned long long)(N0 + nf*16 + lr) * KPAD + lk*8;

  f32x4 acc[4][8];
#pragma unroll
  for (int mf = 0; mf < 4; ++mf)
#pragma unroll
    for (int nf = 0; nf < 8; ++nf)
      acc[mf][nf] = (f32x4){0.f, 0.f, 0.f, 0.f};

  f32x4 a0[4][2];
  f16x8 aF[4], bF[8];

#pragma unroll
  for (int mf = 0; mf < 4; ++mf){
    a0[mf][0] = *(const f32x4*)(ax[mf]);
    a0[mf][1] = *(const f32x4*)(ax[mf] + 4);
  }
#pragma unroll
  for (int nf = 0; nf < 8; ++nf)
    bF[nf] = *(const f16x8*)(bx[nf]);
#pragma unroll
  for (int mf = 0; mf < 4; ++mf){
    f32x4 lo = a0[mf][0], hi = a0[mf][1];
    f16x8 v; v[0]=(f16)lo.x; v[1]=(f16)lo.y; v[2]=(f16)lo.z; v[3]=(f16)lo.w;
             v[4]=(f16)hi.x; v[5]=(f16)hi.y; v[6]=(f16)hi.z; v[7]=(f16)hi.w;
    aF[mf] = v;
  }

  for (int kc = 0; kc < 22; ++kc){
    if (kc < 21){                               // issue next A (long-latency) early
#pragma unroll
      for (int mf = 0; mf < 4; ++mf){
        a0[mf][0] = *(const f32x4*)(ax[mf] + (kc+1)*32);
        a0[mf][1] = *(const f32x4*)(ax[mf] + (kc+1)*32 + 4);
      }
    }
#pragma unroll
    for (int nf = 0; nf < 8; ++nf){
#pragma unroll
      for (int mf = 0; mf < 4; ++mf)
        acc[mf][nf] = __builtin_amdgcn_mfma_f32_16x16x32_f16(aF[mf], bF[nf], acc[mf][nf], 0, 0, 0);
      if (kc < 21)                              // reload B right after last use (L2-hit)
        bF[nf] = *(const f16x8*)(bx[nf] + (kc+1)*32);
    }
    if (kc < 21){
#pragma unroll
      for (int mf = 0; mf < 4; ++mf){
        f32x4 lo = a0[mf][0], hi = a0[mf][1];
        f16x8 v; v[0]=(f16)lo.x; v[1]=(f16)lo.y; v[2]=(f16)lo.z; v[3]=(f16)lo.w;
                 v[4]=(f16)hi.x; v[5]=(f16)hi.y; v[6]=(f16)hi.z; v[7]=(f16)hi.w;
        aF[mf] = v;
      }
    }
  }

  { // K tail: k = 704..719 valid (lanes lk<2), wxt zero-padded to 736
    f16x8 aT[4];
#pragma unroll
    for (int mf = 0; mf < 4; ++mf) aT[mf] = (f16x8)(f16)0.f;
    if (lk < 2){
#pragma unroll
      for (int mf = 0; mf < 4; ++mf){
        f32x4 lo = *(const f32x4*)(ax[mf] + 704);
        f32x4 hi = *(const f32x4*)(ax[mf] + 708);
        f16x8 v; v[0]=(f16)lo.x; v[1]=(f16)lo.y; v[2]=(f16)lo.z; v[3]=(f16)lo.w;
                 v[4]=(f16)hi.x; v[5]=(f16)hi.y; v[6]=(f16)hi.z; v[7]=(f16)hi.w;
        aT[mf] = v;
      }
    }
#pragma unroll
    for (int nf = 0; nf < 8; ++nf){
      f16x8 bT = *(const f16x8*)(bx[nf] + 704);
#pragma unroll
      for (int mf = 0; mf < 4; ++mf)
        acc[mf][nf] = __builtin_amdgcn_mfma_f32_16x16x32_f16(aT[mf], bT, acc[mf][nf], 0, 0, 0);
    }
  }

  // Fragment-native epilogue: lane l holds (row = M0+mf*16+lk*4+rr, col = N0+nf*16+lr).
  // s = mb; b0 = 4*w+mf; frag f = 8*nb+nf; +bias; pack rr0..3 -> 8B; coalesced store.
  float bs[8];
#pragma unroll
  for (int nf = 0; nf < 8; ++nf) bs[nf] = bvec[N0 + nf*16 + lr];
#pragma unroll
  for (int mf = 0; mf < 4; ++mf){
#pragma unroll
    for (int nf = 0; nf < 8; ++nf){
      f32x4 a = acc[mf][nf];
      uint2 v;
      v.x = pkf16(a[0] + bs[nf], a[1] + bs[nf]);
      v.y = pkf16(a[2] + bs[nf], a[3] + bs[nf]);
      unsigned long long off =
        ((unsigned long long)(mb*16u + 4u*(u32)w + (u32)mf) * 32u + (nb*8u + (u32)nf)) * 512ull
        + (unsigned long long)l * 8ull;
      *(uint2*)((char*)xwf + off) = v;
    }
  }
}

// ---------------- K2: LSTM scan via MFMA (16 batch rows/block, 16 waves) + fused heads ----
// Wave w owns gate cols [32w, 32w+32). Wh B-frags persistent in VGPRs (32 regs).
// h fp16 in LDS (padded stride 272B); c/h fp32 state in update-thread registers.
__global__ __launch_bounds__(1024, 1) void k_rnn(
    const u16* __restrict__ xwf, const float* __restrict__ Wh,
    const float* __restrict__ h0, const float* __restrict__ c0,
    const float* __restrict__ Wa1, const float* __restrict__ ba1,
    const float* __restrict__ Wa2, const float* __restrict__ ba2,
    const float* __restrict__ Wc1, const float* __restrict__ bc1,
    const float* __restrict__ Wc2, const float* __restrict__ bc2,
    const float* __restrict__ log_std, float* __restrict__ out)
{
  const int b0 = blockIdx.x;          // 16 blocks
  const int t  = threadIdx.x;         // 0..1023
  const int w  = t >> 6;              // wave 0..15
  const int l  = t & 63;
  const int lr = l & 15;
  const int g4 = l >> 4;              // 0..3

  __shared__ __align__(16) u16   h16[16 * 136];   // h fp16, row stride 136 halves (272B)
  __shared__ __align__(16) float act[16 * 516];   // activated gates, row stride 516 f32
  __shared__ __align__(16) float hfin[16 * 128];  // final h fp32 (heads)
  __shared__ float hid2[16 * 256];                // heads hidden

  // ---- persistent Wh B-fragments: col = 32w + 16*nf2 + lr, k = kk*32 + g4*8 + j ----
  f16x8 wb[4][2];
  {
    const int col0 = 32*w + lr;
#pragma unroll
    for (int nf2 = 0; nf2 < 2; ++nf2){
      const int col = col0 + 16*nf2;
#pragma unroll
      for (int kk = 0; kk < 4; ++kk){
        f16x8 v;
#pragma unroll
        for (int j = 0; j < 8; ++j)
          v[j] = (f16)Wh[(u32)(kk*32 + g4*8 + j) * G4 + col];
        wb[kk][nf2] = v;
      }
    }
  }

  // ---- state: thread owns (batch row bb = 16*b0 + w, h-cols 2l, 2l+1) ----
  const int bb = b0*16 + w;
  float c0v = c0[bb*HID + 2*l], c1v = c0[bb*HID + 2*l + 1];
  float h0v = h0[bb*HID + 2*l], h1v = h0[bb*HID + 2*l + 1];
  *(u32*)((char*)h16 + w*272 + l*4) = pkf16(h0v, h1v);
  __syncthreads();

  const char* xp = (const char*)xwf
                 + ((unsigned long long)b0 * 32u + 2u*(u32)w) * 512ull + (u32)l * 8u;
  uint2 xq0 = *(const uint2*)(xp);
  uint2 xq1 = *(const uint2*)(xp + 512);
  const u32 region = (u32)w >> 2;     // 0:i 1:f 2:g 3:o  (wave-uniform)

  for (int s = 0; s < T_STEPS; ++s){
    // A-fragments: h16[row=lr][k = kk*32 + g4*8 + j]
    f16x8 af[4];
#pragma unroll
    for (int kk = 0; kk < 4; ++kk)
      af[kk] = *(const f16x8*)((const char*)h16 + lr*272 + kk*64 + g4*16);

    uint2 xn0, xn1; xn0.x=xn0.y=xn1.x=xn1.y=0u;
    if (s + 1 < T_STEPS){
      const char* xnp = xp + (u32)(s+1) * 262144u;   // 16*32*512 B per step
      xn0 = *(const uint2*)(xnp);
      xn1 = *(const uint2*)(xnp + 512);
    }

    f32x4 acc0, acc1;   // C init = xW + b (from gemm epilogue)
    acc0 = (f32x4){lo16f(xq0.x), hi16f(xq0.x), lo16f(xq0.y), hi16f(xq0.y)};
    acc1 = (f32x4){lo16f(xq1.x), hi16f(xq1.x), lo16f(xq1.y), hi16f(xq1.y)};
#pragma unroll
    for (int kk = 0; kk < 4; ++kk){
      acc0 = __builtin_amdgcn_mfma_f32_16x16x32_f16(af[kk], wb[kk][0], acc0, 0, 0, 0);
      acc1 = __builtin_amdgcn_mfma_f32_16x16x32_f16(af[kk], wb[kk][1], acc1, 0, 0, 0);
    }

    // activation + scatter to act LDS (C layout: row = g4*4+rr, col = 32w+16nf2+lr)
#pragma unroll
    for (int rr = 0; rr < 4; ++rr){
      float* ap = act + (g4*4 + rr)*516 + 32*w + lr;
      float v0 = acc0[rr], v1 = acc1[rr];
      if (region == 2){ v0 = tanhfast(v0); v1 = tanhfast(v1); }
      else            { v0 = sigf(v0);     v1 = sigf(v1);     }
      ap[0]  = v0;
      ap[16] = v1;
    }
    __syncthreads();
    { // c/h update: row w, cols 2l, 2l+1
      const float* ar = act + w*516 + 2*l;
      f32x2 gi = *(const f32x2*)(ar);
      f32x2 gf = *(const f32x2*)(ar + 128);
      f32x2 gg = *(const f32x2*)(ar + 256);
      f32x2 go = *(const f32x2*)(ar + 384);
      c0v = gf.x*c0v + gi.x*gg.x;
      c1v = gf.y*c1v + gi.y*gg.y;
      h0v = go.x*tanhfast(c0v);
      h1v = go.y*tanhfast(c1v);
      *(u32*)((char*)h16 + w*272 + l*4) = pkf16(h0v, h1v);
    }
    __syncthreads();
    xq0 = xn0; xq1 = xn1;
  }

  // ---- outputs hT/cT (exact fp32 state) ----
  f32x2 hvv; hvv.x = h0v; hvv.y = h1v;
  f32x2 cvv; cvv.x = c0v; cvv.y = c1v;
  *(f32x2*)(out + OUT_HT + bb*HID + 2*l) = hvv;
  *(f32x2*)(out + OUT_CT + bb*HID + 2*l) = cvv;
  *(f32x2*)(hfin + w*HID + 2*l) = hvv;
  __syncthreads();

  // ---- heads layer 1 (fp32): 4096 dots / 1024 thr = 4 rows each ----
  {
    const int hc  = t & 255;                 // 0-127 actor, 128-255 critic
    const int r2  = t >> 8;                  // 0..3
    const float* W = (hc < HID) ? Wa1 : Wc1;
    const int col = hc & (HID-1);
    float a0=0.f, a1=0.f, a2=0.f, a3=0.f;
    for (int k = 0; k < HID; ++k){
      float wv = W[(u32)k*HID + col];
      a0 = fmaf(hfin[(r2     )*HID + k], wv, a0);
      a1 = fmaf(hfin[(r2 + 4 )*HID + k], wv, a1);
      a2 = fmaf(hfin[(r2 + 8 )*HID + k], wv, a2);
      a3 = fmaf(hfin[(r2 + 12)*HID + k], wv, a3);
    }
    float bsv = (hc < HID) ? ba1[col] : bc1[col];
    hid2[(r2     )*256 + hc] = tanhfast(a0 + bsv);
    hid2[(r2 + 4 )*256 + hc] = tanhfast(a1 + bsv);
    hid2[(r2 + 8 )*256 + hc] = tanhfast(a2 + bsv);
    hid2[(r2 + 12)*256 + hc] = tanhfast(a3 + bsv);
  }
  __syncthreads();

  // ---- heads layer 2 ----
  if (t < 48){
    const int a = t >> 4, r = t & 15;
    float s = 0.f;
    if (a < 2){
      for (int k = 0; k < HID; ++k) s = fmaf(hid2[r*256 + k], Wa2[k*2 + a], s);
      out[(b0*16 + r)*2 + a] = s + ba2[a];
    } else {
      for (int k = 0; k < HID; ++k) s = fmaf(hid2[r*256 + 128 + k], Wc2[k], s);
      out[OUT_VAL + b0*16 + r] = s + bc2[0];
    }
  }
  if (b0 == 0 && t >= 64 && t < 66) out[OUT_STD + (t - 64)] = expf(log_std[t - 64]);
}

extern "C" void kernel_launch(void* const* d_in, const int* in_sizes, int n_in,
                              void* d_out, int out_size, void* d_ws, size_t ws_size,
                              hipStream_t stream)
{
  (void)in_sizes; (void)n_in; (void)out_size; (void)ws_size;
  const float* x    = (const float*)d_in[0];
  const float* h0   = (const float*)d_in[1];
  const float* c0   = (const float*)d_in[2];
  const float* Wx   = (const float*)d_in[3];
  const float* Wh   = (const float*)d_in[4];
  const float* bv   = (const float*)d_in[5];
  const float* Wa1  = (const float*)d_in[6];
  const float* ba1  = (const float*)d_in[7];
  const float* Wa2  = (const float*)d_in[8];
  const float* ba2  = (const float*)d_in[9];
  const float* lstd = (const float*)d_in[10];
  const float* Wc1  = (const float*)d_in[11];
  const float* bc1  = (const float*)d_in[12];
  const float* Wc2  = (const float*)d_in[13];
  const float* bc2  = (const float*)d_in[14];
  float* out = (float*)d_out;
  char*  ws  = (char*)d_ws;

  u16* xwf = (u16*)(ws + XW_OFF);
  u16* wxt = (u16*)(ws + WXT_OFF);

  k_pack_wxt<<<dim3(512),  dim3(256),  0, stream>>>(Wx, wxt);
  k_gemm<<<dim3(2048),     dim3(256),  0, stream>>>(x, wxt, bv, xwf);
  k_rnn<<<dim3(16),        dim3(1024), 0, stream>>>(xwf, Wh, h0, c0,
                                                    Wa1, ba1, Wa2, ba2, Wc1, bc1, Wc2, bc2,
                                                    lstd, out);
}

// Round 6
// 863.583 us; speedup vs baseline: 1.3374x; 1.3374x over previous
//
#include <hip/hip_runtime.h>
#include <hip/hip_bf16.h>

typedef unsigned int   u32;
typedef unsigned short u16;
typedef _Float16       f16;
typedef __attribute__((ext_vector_type(8))) _Float16 f16x8;
typedef __attribute__((ext_vector_type(4))) float    f32x4;

#define T_STEPS 512
#define BATCH   256
#define O_IN    720
#define KPAD    736      // 720 padded to mult of 32 (zero pad in wxt)
#define HID     128
#define G4      512      // 4*HID
// d_out layout (floats): am[512] | std[2] | value[256] | hT[32768] | cT[32768]
#define OUT_STD 512
#define OUT_VAL 514
#define OUT_HT  770
#define OUT_CT  33538

// ws layout (bytes); requires ws_size >= ~135 MB
static const unsigned long long XW_OFF  = 0ull;          // f16 [131072][512] = 134217728 B
static const unsigned long long WXT_OFF = 134217728ull;  // f16 [512][736]    = 753664 B

__device__ inline float exp2fast(float x){
#if __has_builtin(__builtin_amdgcn_exp2f)
  return __builtin_amdgcn_exp2f(x);
#else
  return exp2f(x);
#endif
}
__device__ inline float sigf(float x){ return 1.0f / (1.0f + exp2fast(-1.44269504f * x)); }
__device__ inline float tanhfast(float x){ return 2.0f / (1.0f + exp2fast(-2.88539008f * x)) - 1.0f; }

// padded h layout: float j lives at byte j*4 + (j>>5)*16  (16B pad per 32 floats)
// -> quarter q base = 144q; in-quarter 128B contiguous; wave reads hit 16 distinct banks.
#define HQ_STRIDE 144
#define H_BYTES   (4*HQ_STRIDE)
#define HOFF(j)   ((j)*4 + ((j)>>5)*16)

// ---------------- K0: Wx (720,512) f32 -> Wx^T f16 [512][736] zero-padded ----------------
__global__ void k_pack_wxt(const float* __restrict__ Wx, u16* __restrict__ wxt){
  const int n = blockIdx.x;               // 512 blocks
  for (int k = threadIdx.x; k < KPAD; k += 256){
    float v = (k < O_IN) ? Wx[(size_t)k * G4 + n] : 0.f;
    wxt[(size_t)n * KPAD + k] = __builtin_bit_cast(u16, (f16)v);
  }
}

// ---------------- K1: xW = x @ Wx  (fp16 MFMA, LDS-free, no barriers) --------------------
// Unchanged from R3 (validated, outputs pass through it).
__global__ __launch_bounds__(256, 2) void k_gemm(const float* __restrict__ x,
                                                 const u16* __restrict__ wxt,
                                                 u16* __restrict__ xw)
{
  const int l  = threadIdx.x & 63;
  const int w  = threadIdx.x >> 6;
  const int lr = l & 15;
  const int lk = l >> 4;
  const u32 L  = (blockIdx.x & 7u) * 256u + (blockIdx.x >> 3);
  const u32 mb = L >> 2, nb = L & 3u;
  const u32 M0 = mb * 256u + (u32)w * 64u;
  const u32 N0 = nb * 128u;

  const float* ax[4];
  const u16*   bx[8];
#pragma unroll
  for (int mf = 0; mf < 4; ++mf)
    ax[mf] = x + (unsigned long long)(M0 + mf*16 + lr) * O_IN + lk*8;
#pragma unroll
  for (int nf = 0; nf < 8; ++nf)
    bx[nf] = wxt + (unsigned long long)(N0 + nf*16 + lr) * KPAD + lk*8;

  f32x4 acc[4][8];
#pragma unroll
  for (int mf = 0; mf < 4; ++mf)
#pragma unroll
    for (int nf = 0; nf < 8; ++nf)
      acc[mf][nf] = (f32x4){0.f, 0.f, 0.f, 0.f};

  f32x4 a0[4][2];
  f16x8 aF[4], bF[8];

#pragma unroll
  for (int mf = 0; mf < 4; ++mf){
    a0[mf][0] = *(const f32x4*)(ax[mf]);
    a0[mf][1] = *(const f32x4*)(ax[mf] + 4);
  }
#pragma unroll
  for (int nf = 0; nf < 8; ++nf)
    bF[nf] = *(const f16x8*)(bx[nf]);
#pragma unroll
  for (int mf = 0; mf < 4; ++mf){
    f32x4 lo = a0[mf][0], hi = a0[mf][1];
    f16x8 v; v[0]=(f16)lo.x; v[1]=(f16)lo.y; v[2]=(f16)lo.z; v[3]=(f16)lo.w;
             v[4]=(f16)hi.x; v[5]=(f16)hi.y; v[6]=(f16)hi.z; v[7]=(f16)hi.w;
    aF[mf] = v;
  }

  for (int kc = 0; kc < 22; ++kc){
    if (kc < 21){
#pragma unroll
      for (int mf = 0; mf < 4; ++mf){
        a0[mf][0] = *(const f32x4*)(ax[mf] + (kc+1)*32);
        a0[mf][1] = *(const f32x4*)(ax[mf] + (kc+1)*32 + 4);
      }
    }
#pragma unroll
    for (int nf = 0; nf < 8; ++nf){
#pragma unroll
      for (int mf = 0; mf < 4; ++mf)
        acc[mf][nf] = __builtin_amdgcn_mfma_f32_16x16x32_f16(aF[mf], bF[nf], acc[mf][nf], 0, 0, 0);
      if (kc < 21)
        bF[nf] = *(const f16x8*)(bx[nf] + (kc+1)*32);
    }
    if (kc < 21){
#pragma unroll
      for (int mf = 0; mf < 4; ++mf){
        f32x4 lo = a0[mf][0], hi = a0[mf][1];
        f16x8 v; v[0]=(f16)lo.x; v[1]=(f16)lo.y; v[2]=(f16)lo.z; v[3]=(f16)lo.w;
                 v[4]=(f16)hi.x; v[5]=(f16)hi.y; v[6]=(f16)hi.z; v[7]=(f16)hi.w;
        aF[mf] = v;
      }
    }
  }

  {
    f16x8 aT[4];
#pragma unroll
    for (int mf = 0; mf < 4; ++mf) aT[mf] = (f16x8)(f16)0.f;
    if (lk < 2){
#pragma unroll
      for (int mf = 0; mf < 4; ++mf){
        f32x4 lo = *(const f32x4*)(ax[mf] + 704);
        f32x4 hi = *(const f32x4*)(ax[mf] + 708);
        f16x8 v; v[0]=(f16)lo.x; v[1]=(f16)lo.y; v[2]=(f16)lo.z; v[3]=(f16)lo.w;
                 v[4]=(f16)hi.x; v[5]=(f16)hi.y; v[6]=(f16)hi.z; v[7]=(f16)hi.w;
        aT[mf] = v;
      }
    }
#pragma unroll
    for (int nf = 0; nf < 8; ++nf){
      f16x8 bT = *(const f16x8*)(bx[nf] + 704);
#pragma unroll
      for (int mf = 0; mf < 4; ++mf)
        acc[mf][nf] = __builtin_amdgcn_mfma_f32_16x16x32_f16(aT[mf], bT, acc[mf][nf], 0, 0, 0);
    }
  }

#pragma unroll
  for (int mf = 0; mf < 4; ++mf){
    const u32 rowb = M0 + mf*16 + lk*4;
#pragma unroll
    for (int nf = 0; nf < 8; ++nf){
      const u32 col = N0 + nf*16 + lr;
#pragma unroll
      for (int r = 0; r < 4; ++r)
        xw[(unsigned long long)(rowb + r) * G4 + col] = __builtin_bit_cast(u16, (f16)acc[mf][nf][r]);
    }
  }
}

// ---------------- K2: LSTM scan, fp32, split-K + shfl reduce (1 row/CU, 512 thr) ----------
// thread t: j = t>>2 (h col), q = t&3 (k-quarter and gate-slot). Per step:
//   8x ds_read_b128 (quarter of h, padded conflict-free) -> 4 gate partials (32 fma each)
//   shfl_xor x2 reduce across 4 adjacent lanes -> activation (1/lane) -> shfl share
//   -> replicated c/h update -> q==0 writes h to double-buffered LDS -> ONE barrier.
__global__ __launch_bounds__(512) void k_rnn(
    const u16* __restrict__ xw, const float* __restrict__ Wh,
    const float* __restrict__ h0, const float* __restrict__ c0,
    const float* __restrict__ bvec,
    const float* __restrict__ Wa1, const float* __restrict__ ba1,
    const float* __restrict__ Wa2, const float* __restrict__ ba2,
    const float* __restrict__ Wc1, const float* __restrict__ bc1,
    const float* __restrict__ Wc2, const float* __restrict__ bc2,
    const float* __restrict__ log_std, float* __restrict__ out)
{
  const int b = blockIdx.x;
  const int t = threadIdx.x;          // 0..511
  const int j = t >> 2;               // h/gate column 0..127
  const int q = t & 3;                // k-quarter & gate slot
  const int l = t & 63;               // lane
  const int lbase = l & ~3;           // partner group base lane

  __shared__ __align__(16) char hbuf[2][H_BYTES];  // h fp32, padded, double-buffered
  __shared__ __align__(16) float hf[HID];          // final h (heads)
  __shared__ float hid[256];

  // ---- weights: w[g][kk] = Wh[32q+kk][j+128g], fp32, fully static ----
  float w0[32], w1[32], w2[32], w3[32];
#pragma unroll
  for (int kk = 0; kk < 32; ++kk){
    const u32 krow = (u32)(32*q + kk) * G4 + (u32)j;
    w0[kk] = Wh[krow];
    w1[kk] = Wh[krow + 128];
    w2[kk] = Wh[krow + 256];
    w3[kk] = Wh[krow + 384];
  }
  const float bb = bvec[j + 128*q];   // bias for this thread's gate col

  // ---- state (replicated across the 4 partner lanes) ----
  float cs = c0[b*HID + j];
  float hv = h0[b*HID + j];
  if (q == 0)
    *(float*)(hbuf[0] + HOFF(j)) = hv;
  __syncthreads();

  const u16* xp = xw + (u32)b * G4 + (u32)(j + 128*q);
  float xc  = (float)__builtin_bit_cast(f16, xp[0]) + bb;
  float xn1 = (T_STEPS > 1) ? (float)__builtin_bit_cast(f16, xp[131072u]) + bb : 0.f;

  for (int s = 0; s < T_STEPS; ++s){
    const char* hq = hbuf[s & 1] + q * HQ_STRIDE;

    float xn2 = 0.f;
    if (s + 2 < T_STEPS)
      xn2 = (float)__builtin_bit_cast(f16, xp[(u32)(s+2) * 131072u]) + bb;

    float p0 = 0.f, p1 = 0.f, p2 = 0.f, p3 = 0.f;
#pragma unroll
    for (int it = 0; it < 8; ++it){
      f32x4 hh = *(const f32x4*)(hq + it*16);    // 4 distinct addrs/wave, conflict-free
      p0 = fmaf(hh.x, w0[4*it+0], p0);  p0 = fmaf(hh.y, w0[4*it+1], p0);
      p0 = fmaf(hh.z, w0[4*it+2], p0);  p0 = fmaf(hh.w, w0[4*it+3], p0);
      p1 = fmaf(hh.x, w1[4*it+0], p1);  p1 = fmaf(hh.y, w1[4*it+1], p1);
      p1 = fmaf(hh.z, w1[4*it+2], p1);  p1 = fmaf(hh.w, w1[4*it+3], p1);
      p2 = fmaf(hh.x, w2[4*it+0], p2);  p2 = fmaf(hh.y, w2[4*it+1], p2);
      p2 = fmaf(hh.z, w2[4*it+2], p2);  p2 = fmaf(hh.w, w2[4*it+3], p2);
      p3 = fmaf(hh.x, w3[4*it+0], p3);  p3 = fmaf(hh.y, w3[4*it+1], p3);
      p3 = fmaf(hh.z, w3[4*it+2], p3);  p3 = fmaf(hh.w, w3[4*it+3], p3);
    }
    // reduce across the 4 partner lanes (each ends with all-4 totals)
    p0 += __shfl_xor(p0, 1);  p1 += __shfl_xor(p1, 1);
    p2 += __shfl_xor(p2, 1);  p3 += __shfl_xor(p3, 1);
    p0 += __shfl_xor(p0, 2);  p1 += __shfl_xor(p1, 2);
    p2 += __shfl_xor(p2, 2);  p3 += __shfl_xor(p3, 2);

    // this lane activates gate q of col j
    float gsum = (q == 0) ? p0 : (q == 1) ? p1 : (q == 2) ? p2 : p3;
    float gval = gsum + xc;
    float av   = (q == 2) ? tanhfast(gval) : sigf(gval);

    // gather the 4 activated gates from partner lanes
    float ai = __shfl(av, lbase + 0);
    float af = __shfl(av, lbase + 1);
    float ag = __shfl(av, lbase + 2);
    float ao = __shfl(av, lbase + 3);

    cs = af * cs + ai * ag;
    hv = ao * tanhfast(cs);
    if (q == 0)
      *(float*)(hbuf[(s & 1) ^ 1] + HOFF(j)) = hv;
    __syncthreads();                 // h[s+1] visible; prior-buffer reads all done
    xc = xn1; xn1 = xn2;
  }

  if (q == 0){                       // exact fp32 state out
    out[OUT_HT + b*HID + j] = hv;
    out[OUT_CT + b*HID + j] = cs;
    hf[j] = hv;
  }
  __syncthreads();

  if (t < 256){ // heads hidden, fp32: t<128 -> actor col t; else critic col t-128
    const float* W = (t < HID) ? Wa1 : Wc1;
    const int col  = t & (HID - 1);
    const f32x4* hp4 = (const f32x4*)hf;
    float a0 = 0.f, a1 = 0.f, a2 = 0.f, a3 = 0.f;
#pragma unroll
    for (int qq = 0; qq < 32; ++qq){
      f32x4 hh = hp4[qq];
      a0 = fmaf(hh.x, W[(u32)(4*qq+0)*HID + col], a0);
      a1 = fmaf(hh.y, W[(u32)(4*qq+1)*HID + col], a1);
      a2 = fmaf(hh.z, W[(u32)(4*qq+2)*HID + col], a2);
      a3 = fmaf(hh.w, W[(u32)(4*qq+3)*HID + col], a3);
    }
    float a = (a0 + a1) + (a2 + a3);
    hid[t] = (t < HID) ? tanhfast(a + ba1[col]) : tanhfast(a + bc1[col]);
  }
  __syncthreads();

  {
    const int wv = t >> 6, lane = t & 63;
    float p = 0.f;
    if (wv == 0)      p = hid[lane]     * Wa2[lane*2]   + hid[lane+64]     * Wa2[(lane+64)*2];
    else if (wv == 1) p = hid[lane]     * Wa2[lane*2+1] + hid[lane+64]     * Wa2[(lane+64)*2+1];
    else if (wv == 2) p = hid[128+lane] * Wc2[lane]     + hid[128+lane+64] * Wc2[lane+64];
#pragma unroll
    for (int off = 32; off > 0; off >>= 1) p += __shfl_down(p, off);
    if (lane == 0){
      if (wv == 0) out[b*2 + 0]   = p + ba2[0];
      if (wv == 1) out[b*2 + 1]   = p + ba2[1];
      if (wv == 2) out[OUT_VAL+b] = p + bc2[0];
    }
    if (b == 0 && wv == 3 && lane < 2) out[OUT_STD + lane] = expf(log_std[lane]);
  }
}

extern "C" void kernel_launch(void* const* d_in, const int* in_sizes, int n_in,
                              void* d_out, int out_size, void* d_ws, size_t ws_size,
                              hipStream_t stream)
{
  (void)in_sizes; (void)n_in; (void)out_size; (void)ws_size;
  const float* x    = (const float*)d_in[0];
  const float* h0   = (const float*)d_in[1];
  const float* c0   = (const float*)d_in[2];
  const float* Wx   = (const float*)d_in[3];
  const float* Wh   = (const float*)d_in[4];
  const float* bv   = (const float*)d_in[5];
  const float* Wa1  = (const float*)d_in[6];
  const float* ba1  = (const float*)d_in[7];
  const float* Wa2  = (const float*)d_in[8];
  const float* ba2  = (const float*)d_in[9];
  const float* lstd = (const float*)d_in[10];
  const float* Wc1  = (const float*)d_in[11];
  const float* bc1  = (const float*)d_in[12];
  const float* Wc2  = (const float*)d_in[13];
  const float* bc2  = (const float*)d_in[14];
  float* out = (float*)d_out;
  char*  ws  = (char*)d_ws;

  u16* xw  = (u16*)(ws + XW_OFF);
  u16* wxt = (u16*)(ws + WXT_OFF);

  k_pack_wxt<<<dim3(512),  dim3(256), 0, stream>>>(Wx, wxt);
  k_gemm<<<dim3(2048),     dim3(256), 0, stream>>>(x, wxt, xw);
  k_rnn<<<dim3(256),       dim3(512), 0, stream>>>(xw, Wh, h0, c0, bv,
                                                   Wa1, ba1, Wa2, ba2, Wc1, bc1, Wc2, bc2,
                                                   lstd, out);
}

// Round 7
// 835.097 us; speedup vs baseline: 1.3831x; 1.0341x over previous
//
#include <hip/hip_runtime.h>
#include <hip/hip_bf16.h>

typedef unsigned int   u32;
typedef unsigned short u16;
typedef _Float16       f16;
typedef __attribute__((ext_vector_type(8))) _Float16 f16x8;
typedef __attribute__((ext_vector_type(4))) float    f32x4;

#define T_STEPS 512
#define BATCH   256
#define O_IN    720
#define KPAD    736      // 720 padded to mult of 32 (zero pad in wxt)
#define HID     128
#define G4      512      // 4*HID
// d_out layout (floats): am[512] | std[2] | value[256] | hT[32768] | cT[32768]
#define OUT_STD 512
#define OUT_VAL 514
#define OUT_HT  770
#define OUT_CT  33538

// ws layout (bytes); requires ws_size >= ~135 MB
static const unsigned long long XW_OFF  = 0ull;          // f16 [131072][512] = 134217728 B
static const unsigned long long WXT_OFF = 134217728ull;  // f16 [512][736]    = 753664 B

__device__ inline float exp2fast(float x){
#if __has_builtin(__builtin_amdgcn_exp2f)
  return __builtin_amdgcn_exp2f(x);
#else
  return exp2f(x);
#endif
}
__device__ inline float sigf(float x){ return 1.0f / (1.0f + exp2fast(-1.44269504f * x)); }
__device__ inline float tanhfast(float x){ return 2.0f / (1.0f + exp2fast(-2.88539008f * x)) - 1.0f; }

// padded h layout: float j lives at byte j*4 + (j>>5)*16  (16B pad per 32 floats)
// -> quarter q base = 144q; in-quarter 128B contiguous; wave reads hit 16 distinct banks.
#define HQ_STRIDE 144
#define H_BYTES   (4*HQ_STRIDE)
#define HOFF(j)   ((j)*4 + ((j)>>5)*16)

// ---------------- K0: Wx (720,512) f32 -> Wx^T f16 [512][736] zero-padded ----------------
__global__ void k_pack_wxt(const float* __restrict__ Wx, u16* __restrict__ wxt){
  const int n = blockIdx.x;               // 512 blocks
  for (int k = threadIdx.x; k < KPAD; k += 256){
    float v = (k < O_IN) ? Wx[(size_t)k * G4 + n] : 0.f;
    wxt[(size_t)n * KPAD + k] = __builtin_bit_cast(u16, (f16)v);
  }
}

// ---------------- K1: xW = x @ Wx  (fp16 MFMA, LDS-free, no barriers) --------------------
// Unchanged (validated; outputs pass through it).
__global__ __launch_bounds__(256, 2) void k_gemm(const float* __restrict__ x,
                                                 const u16* __restrict__ wxt,
                                                 u16* __restrict__ xw)
{
  const int l  = threadIdx.x & 63;
  const int w  = threadIdx.x >> 6;
  const int lr = l & 15;
  const int lk = l >> 4;
  const u32 L  = (blockIdx.x & 7u) * 256u + (blockIdx.x >> 3);
  const u32 mb = L >> 2, nb = L & 3u;
  const u32 M0 = mb * 256u + (u32)w * 64u;
  const u32 N0 = nb * 128u;

  const float* ax[4];
  const u16*   bx[8];
#pragma unroll
  for (int mf = 0; mf < 4; ++mf)
    ax[mf] = x + (unsigned long long)(M0 + mf*16 + lr) * O_IN + lk*8;
#pragma unroll
  for (int nf = 0; nf < 8; ++nf)
    bx[nf] = wxt + (unsigned long long)(N0 + nf*16 + lr) * KPAD + lk*8;

  f32x4 acc[4][8];
#pragma unroll
  for (int mf = 0; mf < 4; ++mf)
#pragma unroll
    for (int nf = 0; nf < 8; ++nf)
      acc[mf][nf] = (f32x4){0.f, 0.f, 0.f, 0.f};

  f32x4 a0[4][2];
  f16x8 aF[4], bF[8];

#pragma unroll
  for (int mf = 0; mf < 4; ++mf){
    a0[mf][0] = *(const f32x4*)(ax[mf]);
    a0[mf][1] = *(const f32x4*)(ax[mf] + 4);
  }
#pragma unroll
  for (int nf = 0; nf < 8; ++nf)
    bF[nf] = *(const f16x8*)(bx[nf]);
#pragma unroll
  for (int mf = 0; mf < 4; ++mf){
    f32x4 lo = a0[mf][0], hi = a0[mf][1];
    f16x8 v; v[0]=(f16)lo.x; v[1]=(f16)lo.y; v[2]=(f16)lo.z; v[3]=(f16)lo.w;
             v[4]=(f16)hi.x; v[5]=(f16)hi.y; v[6]=(f16)hi.z; v[7]=(f16)hi.w;
    aF[mf] = v;
  }

  for (int kc = 0; kc < 22; ++kc){
    if (kc < 21){
#pragma unroll
      for (int mf = 0; mf < 4; ++mf){
        a0[mf][0] = *(const f32x4*)(ax[mf] + (kc+1)*32);
        a0[mf][1] = *(const f32x4*)(ax[mf] + (kc+1)*32 + 4);
      }
    }
#pragma unroll
    for (int nf = 0; nf < 8; ++nf){
#pragma unroll
      for (int mf = 0; mf < 4; ++mf)
        acc[mf][nf] = __builtin_amdgcn_mfma_f32_16x16x32_f16(aF[mf], bF[nf], acc[mf][nf], 0, 0, 0);
      if (kc < 21)
        bF[nf] = *(const f16x8*)(bx[nf] + (kc+1)*32);
    }
    if (kc < 21){
#pragma unroll
      for (int mf = 0; mf < 4; ++mf){
        f32x4 lo = a0[mf][0], hi = a0[mf][1];
        f16x8 v; v[0]=(f16)lo.x; v[1]=(f16)lo.y; v[2]=(f16)lo.z; v[3]=(f16)lo.w;
                 v[4]=(f16)hi.x; v[5]=(f16)hi.y; v[6]=(f16)hi.z; v[7]=(f16)hi.w;
        aF[mf] = v;
      }
    }
  }

  {
    f16x8 aT[4];
#pragma unroll
    for (int mf = 0; mf < 4; ++mf) aT[mf] = (f16x8)(f16)0.f;
    if (lk < 2){
#pragma unroll
      for (int mf = 0; mf < 4; ++mf){
        f32x4 lo = *(const f32x4*)(ax[mf] + 704);
        f32x4 hi = *(const f32x4*)(ax[mf] + 708);
        f16x8 v; v[0]=(f16)lo.x; v[1]=(f16)lo.y; v[2]=(f16)lo.z; v[3]=(f16)lo.w;
                 v[4]=(f16)hi.x; v[5]=(f16)hi.y; v[6]=(f16)hi.z; v[7]=(f16)hi.w;
        aT[mf] = v;
      }
    }
#pragma unroll
    for (int nf = 0; nf < 8; ++nf){
      f16x8 bT = *(const f16x8*)(bx[nf] + 704);
#pragma unroll
      for (int mf = 0; mf < 4; ++mf)
        acc[mf][nf] = __builtin_amdgcn_mfma_f32_16x16x32_f16(aT[mf], bT, acc[mf][nf], 0, 0, 0);
    }
  }

#pragma unroll
  for (int mf = 0; mf < 4; ++mf){
    const u32 rowb = M0 + mf*16 + lk*4;
#pragma unroll
    for (int nf = 0; nf < 8; ++nf){
      const u32 col = N0 + nf*16 + lr;
#pragma unroll
      for (int r = 0; r < 4; ++r)
        xw[(unsigned long long)(rowb + r) * G4 + col] = __builtin_bit_cast(u16, (f16)acc[mf][nf][r]);
    }
  }
}

// ---------------- K2: LSTM scan, fp32, split-K + shfl reduce (1 row/CU, 512 thr) ----------
// __launch_bounds__(512, 2): 2 waves/SIMD -> 256-VGPR cap so the 128 weight regs
// stay RESIDENT (R3/R6 at default bounds spilled them; VGPR_Count 84/96 = smoking gun).
__global__ __launch_bounds__(512, 2) void k_rnn(
    const u16* __restrict__ xw, const float* __restrict__ Wh,
    const float* __restrict__ h0, const float* __restrict__ c0,
    const float* __restrict__ bvec,
    const float* __restrict__ Wa1, const float* __restrict__ ba1,
    const float* __restrict__ Wa2, const float* __restrict__ ba2,
    const float* __restrict__ Wc1, const float* __restrict__ bc1,
    const float* __restrict__ Wc2, const float* __restrict__ bc2,
    const float* __restrict__ log_std, float* __restrict__ out)
{
  const int b = blockIdx.x;
  const int t = threadIdx.x;          // 0..511
  const int j = t >> 2;               // h/gate column 0..127
  const int q = t & 3;                // k-quarter & gate slot
  const int l = t & 63;               // lane
  const int lbase = l & ~3;           // partner group base lane

  __shared__ __align__(16) char hbuf[2][H_BYTES];  // h fp32, padded, double-buffered
  __shared__ __align__(16) float hf[HID];          // final h (heads)
  __shared__ float hid[256];

  // ---- weights: w[g][kk] = Wh[32q+kk][j+128g], fp32, fully static ----
  float w0[32], w1[32], w2[32], w3[32];
#pragma unroll
  for (int kk = 0; kk < 32; ++kk){
    const u32 krow = (u32)(32*q + kk) * G4 + (u32)j;
    w0[kk] = Wh[krow];
    w1[kk] = Wh[krow + 128];
    w2[kk] = Wh[krow + 256];
    w3[kk] = Wh[krow + 384];
  }
  const float bb = bvec[j + 128*q];   // bias for this thread's gate col

  // branchless activation constants: gate q==2 -> tanh(g)=2*sig(2g)-1, else sigmoid
  const float kexp  = (q == 2) ? -2.88539008f : -1.44269504f;
  const float postm = (q == 2) ? 2.f : 1.f;
  const float posta = (q == 2) ? -1.f : 0.f;

  // ---- state (replicated across the 4 partner lanes) ----
  float cs = c0[b*HID + j];
  float hv = h0[b*HID + j];
  if (q == 0)
    *(float*)(hbuf[0] + HOFF(j)) = hv;
  __syncthreads();

  const u16* xp = xw + (u32)b * G4 + (u32)(j + 128*q);
  float xc  = (float)__builtin_bit_cast(f16, xp[0]) + bb;
  float xn1 = (T_STEPS > 1) ? (float)__builtin_bit_cast(f16, xp[131072u]) + bb : 0.f;

  for (int s = 0; s < T_STEPS; ++s){
    const char* hq = hbuf[s & 1] + q * HQ_STRIDE;

    float xn2 = 0.f;
    if (s + 2 < T_STEPS)
      xn2 = (float)__builtin_bit_cast(f16, xp[(u32)(s+2) * 131072u]) + bb;

    float p0 = 0.f, p1 = 0.f, p2 = 0.f, p3 = 0.f;
#pragma unroll
    for (int it = 0; it < 8; ++it){
      f32x4 hh = *(const f32x4*)(hq + it*16);    // 4 distinct addrs/wave, conflict-free
      p0 = fmaf(hh.x, w0[4*it+0], p0);  p0 = fmaf(hh.y, w0[4*it+1], p0);
      p0 = fmaf(hh.z, w0[4*it+2], p0);  p0 = fmaf(hh.w, w0[4*it+3], p0);
      p1 = fmaf(hh.x, w1[4*it+0], p1);  p1 = fmaf(hh.y, w1[4*it+1], p1);
      p1 = fmaf(hh.z, w1[4*it+2], p1);  p1 = fmaf(hh.w, w1[4*it+3], p1);
      p2 = fmaf(hh.x, w2[4*it+0], p2);  p2 = fmaf(hh.y, w2[4*it+1], p2);
      p2 = fmaf(hh.z, w2[4*it+2], p2);  p2 = fmaf(hh.w, w2[4*it+3], p2);
      p3 = fmaf(hh.x, w3[4*it+0], p3);  p3 = fmaf(hh.y, w3[4*it+1], p3);
      p3 = fmaf(hh.z, w3[4*it+2], p3);  p3 = fmaf(hh.w, w3[4*it+3], p3);
    }
    // reduce across the 4 partner lanes (each ends with all-4 totals)
    p0 += __shfl_xor(p0, 1);  p1 += __shfl_xor(p1, 1);
    p2 += __shfl_xor(p2, 1);  p3 += __shfl_xor(p3, 1);
    p0 += __shfl_xor(p0, 2);  p1 += __shfl_xor(p1, 2);
    p2 += __shfl_xor(p2, 2);  p3 += __shfl_xor(p3, 2);

    // this lane activates gate q of col j (branchless: 1 exp + 1 rcp)
    float gsum = (q == 0) ? p0 : (q == 1) ? p1 : (q == 2) ? p2 : p3;
    float gval = gsum + xc;
    float r    = 1.0f / (1.0f + exp2fast(kexp * gval));
    float av   = fmaf(postm, r, posta);

    // gather the 4 activated gates from partner lanes
    float ai = __shfl(av, lbase + 0);
    float af = __shfl(av, lbase + 1);
    float ag = __shfl(av, lbase + 2);
    float ao = __shfl(av, lbase + 3);

    cs = af * cs + ai * ag;
    hv = ao * tanhfast(cs);
    if (q == 0)
      *(float*)(hbuf[(s & 1) ^ 1] + HOFF(j)) = hv;
    __syncthreads();                 // h[s+1] visible; prior-buffer reads all done
    xc = xn1; xn1 = xn2;
  }

  if (q == 0){                       // exact fp32 state out
    out[OUT_HT + b*HID + j] = hv;
    out[OUT_CT + b*HID + j] = cs;
    hf[j] = hv;
  }
  __syncthreads();

  if (t < 256){ // heads hidden, fp32: t<128 -> actor col t; else critic col t-128
    const float* W = (t < HID) ? Wa1 : Wc1;
    const int col  = t & (HID - 1);
    const f32x4* hp4 = (const f32x4*)hf;
    float a0 = 0.f, a1 = 0.f, a2 = 0.f, a3 = 0.f;
#pragma unroll
    for (int qq = 0; qq < 32; ++qq){
      f32x4 hh = hp4[qq];
      a0 = fmaf(hh.x, W[(u32)(4*qq+0)*HID + col], a0);
      a1 = fmaf(hh.y, W[(u32)(4*qq+1)*HID + col], a1);
      a2 = fmaf(hh.z, W[(u32)(4*qq+2)*HID + col], a2);
      a3 = fmaf(hh.w, W[(u32)(4*qq+3)*HID + col], a3);
    }
    float a = (a0 + a1) + (a2 + a3);
    hid[t] = (t < HID) ? tanhfast(a + ba1[col]) : tanhfast(a + bc1[col]);
  }
  __syncthreads();

  {
    const int wv = t >> 6, lane = t & 63;
    float p = 0.f;
    if (wv == 0)      p = hid[lane]     * Wa2[lane*2]   + hid[lane+64]     * Wa2[(lane+64)*2];
    else if (wv == 1) p = hid[lane]     * Wa2[lane*2+1] + hid[lane+64]     * Wa2[(lane+64)*2+1];
    else if (wv == 2) p = hid[128+lane] * Wc2[lane]     + hid[128+lane+64] * Wc2[lane+64];
#pragma unroll
    for (int off = 32; off > 0; off >>= 1) p += __shfl_down(p, off);
    if (lane == 0){
      if (wv == 0) out[b*2 + 0]   = p + ba2[0];
      if (wv == 1) out[b*2 + 1]   = p + ba2[1];
      if (wv == 2) out[OUT_VAL+b] = p + bc2[0];
    }
    if (b == 0 && wv == 3 && lane < 2) out[OUT_STD + lane] = expf(log_std[lane]);
  }
}

extern "C" void kernel_launch(void* const* d_in, const int* in_sizes, int n_in,
                              void* d_out, int out_size, void* d_ws, size_t ws_size,
                              hipStream_t stream)
{
  (void)in_sizes; (void)n_in; (void)out_size; (void)ws_size;
  const float* x    = (const float*)d_in[0];
  const float* h0   = (const float*)d_in[1];
  const float* c0   = (const float*)d_in[2];
  const float* Wx   = (const float*)d_in[3];
  const float* Wh   = (const float*)d_in[4];
  const float* bv   = (const float*)d_in[5];
  const float* Wa1  = (const float*)d_in[6];
  const float* ba1  = (const float*)d_in[7];
  const float* Wa2  = (const float*)d_in[8];
  const float* ba2  = (const float*)d_in[9];
  const float* lstd = (const float*)d_in[10];
  const float* Wc1  = (const float*)d_in[11];
  const float* bc1  = (const float*)d_in[12];
  const float* Wc2  = (const float*)d_in[13];
  const float* bc2  = (const float*)d_in[14];
  float* out = (float*)d_out;
  char*  ws  = (char*)d_ws;

  u16* xw  = (u16*)(ws + XW_OFF);
  u16* wxt = (u16*)(ws + WXT_OFF);

  k_pack_wxt<<<dim3(512),  dim3(256), 0, stream>>>(Wx, wxt);
  k_gemm<<<dim3(2048),     dim3(256), 0, stream>>>(x, wxt, xw);
  k_rnn<<<dim3(256),       dim3(512), 0, stream>>>(xw, Wh, h0, c0, bv,
                                                   Wa1, ba1, Wa2, ba2, Wc1, bc1, Wc2, bc2,
                                                   lstd, out);
}

// Round 9
// 824.534 us; speedup vs baseline: 1.4008x; 1.0128x over previous
//
#include <hip/hip_runtime.h>
#include <hip/hip_bf16.h>

typedef unsigned int   u32;
typedef unsigned short u16;
typedef _Float16       f16;
typedef __attribute__((ext_vector_type(2))) _Float16 f16x2;
typedef __attribute__((ext_vector_type(8))) _Float16 f16x8;
typedef __attribute__((ext_vector_type(4))) float    f32x4;
typedef __attribute__((ext_vector_type(4))) u32      u32x4;

#define T_STEPS 512
#define BATCH   256
#define O_IN    720
#define KPAD    736      // 720 padded to mult of 32 (zero pad in wxt)
#define HID     128
#define G4      512      // 4*HID
// d_out layout (floats): am[512] | std[2] | value[256] | hT[32768] | cT[32768]
#define OUT_STD 512
#define OUT_VAL 514
#define OUT_HT  770
#define OUT_CT  33538

// ws layout (bytes); requires ws_size >= ~135 MB
static const unsigned long long XW_OFF  = 0ull;          // f16 [131072][512] = 134217728 B
static const unsigned long long WXT_OFF = 134217728ull;  // f16 [512][736]    = 753664 B

__device__ inline float exp2fast(float x){
#if __has_builtin(__builtin_amdgcn_exp2f)
  return __builtin_amdgcn_exp2f(x);
#else
  return exp2f(x);
#endif
}
__device__ inline float sigf(float x){ return 1.0f / (1.0f + exp2fast(-1.44269504f * x)); }
__device__ inline float tanhfast(float x){ return 2.0f / (1.0f + exp2fast(-2.88539008f * x)) - 1.0f; }

// d = a.lo*b.lo + a.hi*b.hi + c  (f16 pairs, f32 accum) — INLINE ASM, not the builtin:
// R2/R8 both failed with bit-identical garbage via __builtin_amdgcn_fdot2; R1's
// inline-asm dot2 (bf16) was numerically correct. Same pattern, f16 variant.
__device__ inline float dot2f(u32 a, u32 b, float c){
  float d;
  asm("v_dot2_f32_f16 %0, %1, %2, %3" : "=v"(d) : "v"(a), "v"(b), "v"(c));
  return d;
}

// h stored as f16 in LDS. Quarter q (32 halves = 64B) at byte q*80 (16B pad/quarter):
// 16B-aligned for ds_read_b128; 4 wave-simultaneous quarter addresses are bank-disjoint.
#define HQ_STRIDE 80
#define H_BYTES   (4*HQ_STRIDE)
#define HW_OFF(j) (((j)>>5)*HQ_STRIDE + ((j)&31)*2)

// ---------------- K0: Wx (720,512) f32 -> Wx^T f16 [512][736] zero-padded ----------------
__global__ void k_pack_wxt(const float* __restrict__ Wx, u16* __restrict__ wxt){
  const int n = blockIdx.x;               // 512 blocks
  for (int k = threadIdx.x; k < KPAD; k += 256){
    float v = (k < O_IN) ? Wx[(size_t)k * G4 + n] : 0.f;
    wxt[(size_t)n * KPAD + k] = __builtin_bit_cast(u16, (f16)v);
  }
}

// ---------------- K1: xW = x @ Wx  (fp16 MFMA, LDS-free, no barriers) --------------------
// Unchanged (validated; outputs pass through it).
__global__ __launch_bounds__(256, 2) void k_gemm(const float* __restrict__ x,
                                                 const u16* __restrict__ wxt,
                                                 u16* __restrict__ xw)
{
  const int l  = threadIdx.x & 63;
  const int w  = threadIdx.x >> 6;
  const int lr = l & 15;
  const int lk = l >> 4;
  const u32 L  = (blockIdx.x & 7u) * 256u + (blockIdx.x >> 3);
  const u32 mb = L >> 2, nb = L & 3u;
  const u32 M0 = mb * 256u + (u32)w * 64u;
  const u32 N0 = nb * 128u;

  const float* ax[4];
  const u16*   bx[8];
#pragma unroll
  for (int mf = 0; mf < 4; ++mf)
    ax[mf] = x + (unsigned long long)(M0 + mf*16 + lr) * O_IN + lk*8;
#pragma unroll
  for (int nf = 0; nf < 8; ++nf)
    bx[nf] = wxt + (unsigned long long)(N0 + nf*16 + lr) * KPAD + lk*8;

  f32x4 acc[4][8];
#pragma unroll
  for (int mf = 0; mf < 4; ++mf)
#pragma unroll
    for (int nf = 0; nf < 8; ++nf)
      acc[mf][nf] = (f32x4){0.f, 0.f, 0.f, 0.f};

  f32x4 a0[4][2];
  f16x8 aF[4], bF[8];

#pragma unroll
  for (int mf = 0; mf < 4; ++mf){
    a0[mf][0] = *(const f32x4*)(ax[mf]);
    a0[mf][1] = *(const f32x4*)(ax[mf] + 4);
  }
#pragma unroll
  for (int nf = 0; nf < 8; ++nf)
    bF[nf] = *(const f16x8*)(bx[nf]);
#pragma unroll
  for (int mf = 0; mf < 4; ++mf){
    f32x4 lo = a0[mf][0], hi = a0[mf][1];
    f16x8 v; v[0]=(f16)lo.x; v[1]=(f16)lo.y; v[2]=(f16)lo.z; v[3]=(f16)lo.w;
             v[4]=(f16)hi.x; v[5]=(f16)hi.y; v[6]=(f16)hi.z; v[7]=(f16)hi.w;
    aF[mf] = v;
  }

  for (int kc = 0; kc < 22; ++kc){
    if (kc < 21){
#pragma unroll
      for (int mf = 0; mf < 4; ++mf){
        a0[mf][0] = *(const f32x4*)(ax[mf] + (kc+1)*32);
        a0[mf][1] = *(const f32x4*)(ax[mf] + (kc+1)*32 + 4);
      }
    }
#pragma unroll
    for (int nf = 0; nf < 8; ++nf){
#pragma unroll
      for (int mf = 0; mf < 4; ++mf)
        acc[mf][nf] = __builtin_amdgcn_mfma_f32_16x16x32_f16(aF[mf], bF[nf], acc[mf][nf], 0, 0, 0);
      if (kc < 21)
        bF[nf] = *(const f16x8*)(bx[nf] + (kc+1)*32);
    }
    if (kc < 21){
#pragma unroll
      for (int mf = 0; mf < 4; ++mf){
        f32x4 lo = a0[mf][0], hi = a0[mf][1];
        f16x8 v; v[0]=(f16)lo.x; v[1]=(f16)lo.y; v[2]=(f16)lo.z; v[3]=(f16)lo.w;
                 v[4]=(f16)hi.x; v[5]=(f16)hi.y; v[6]=(f16)hi.z; v[7]=(f16)hi.w;
        aF[mf] = v;
      }
    }
  }

  {
    f16x8 aT[4];
#pragma unroll
    for (int mf = 0; mf < 4; ++mf) aT[mf] = (f16x8)(f16)0.f;
    if (lk < 2){
#pragma unroll
      for (int mf = 0; mf < 4; ++mf){
        f32x4 lo = *(const f32x4*)(ax[mf] + 704);
        f32x4 hi = *(const f32x4*)(ax[mf] + 708);
        f16x8 v; v[0]=(f16)lo.x; v[1]=(f16)lo.y; v[2]=(f16)lo.z; v[3]=(f16)lo.w;
                 v[4]=(f16)hi.x; v[5]=(f16)hi.y; v[6]=(f16)hi.z; v[7]=(f16)hi.w;
        aT[mf] = v;
      }
    }
#pragma unroll
    for (int nf = 0; nf < 8; ++nf){
      f16x8 bT = *(const f16x8*)(bx[nf] + 704);
#pragma unroll
      for (int mf = 0; mf < 4; ++mf)
        acc[mf][nf] = __builtin_amdgcn_mfma_f32_16x16x32_f16(aT[mf], bT, acc[mf][nf], 0, 0, 0);
    }
  }

#pragma unroll
  for (int mf = 0; mf < 4; ++mf){
    const u32 rowb = M0 + mf*16 + lk*4;
#pragma unroll
    for (int nf = 0; nf < 8; ++nf){
      const u32 col = N0 + nf*16 + lr;
#pragma unroll
      for (int r = 0; r < 4; ++r)
        xw[(unsigned long long)(rowb + r) * G4 + col] = __builtin_bit_cast(u16, (f16)acc[mf][nf][r]);
    }
  }
}

// ---------------- K2: LSTM scan, f16 dot2 (inline asm) weights in-reg ---------------------
// thread t: j = t>>2 (gate col), q = t&3 (k-quarter). 64 packed f16x2 weight regs/thread
// (keep-alive pinned), h as f16 in LDS (4x ds_read_b128/step), fp32 accum.
__global__ __launch_bounds__(512, 2) void k_rnn(
    const u16* __restrict__ xw, const float* __restrict__ Wh,
    const float* __restrict__ h0, const float* __restrict__ c0,
    const float* __restrict__ bvec,
    const float* __restrict__ Wa1, const float* __restrict__ ba1,
    const float* __restrict__ Wa2, const float* __restrict__ ba2,
    const float* __restrict__ Wc1, const float* __restrict__ bc1,
    const float* __restrict__ Wc2, const float* __restrict__ bc2,
    const float* __restrict__ log_std, float* __restrict__ out)
{
  const int b = blockIdx.x;
  const int t = threadIdx.x;          // 0..511
  const int j = t >> 2;               // gate/h column 0..127
  const int q = t & 3;                // k-quarter & gate slot
  const int l = t & 63;               // lane
  const int lbase = l & ~3;           // partner group base lane

  __shared__ __align__(16) char hbuf[2][H_BYTES];  // h f16, padded quarters, double-buffered
  __shared__ __align__(16) float hf[HID];          // final h fp32 (heads)
  __shared__ float hid[256];

  // ---- weights: wgN[m] = f16x2{ Wh[32q+2m][j+128N], Wh[32q+2m+1][j+128N] } ----
  u32 wg0[16], wg1[16], wg2[16], wg3[16];
#pragma unroll
  for (int m = 0; m < 16; ++m){
    const u32 kb = (u32)(32*q + 2*m) * G4 + (u32)j;
    f16x2 p;
    p[0]=(f16)Wh[kb      ]; p[1]=(f16)Wh[kb+G4      ]; wg0[m]=__builtin_bit_cast(u32,p);
    p[0]=(f16)Wh[kb+128  ]; p[1]=(f16)Wh[kb+G4+128  ]; wg1[m]=__builtin_bit_cast(u32,p);
    p[0]=(f16)Wh[kb+256  ]; p[1]=(f16)Wh[kb+G4+256  ]; wg2[m]=__builtin_bit_cast(u32,p);
    p[0]=(f16)Wh[kb+384  ]; p[1]=(f16)Wh[kb+G4+384  ]; wg3[m]=__builtin_bit_cast(u32,p);
  }
  // pin: opaque identity so the scheduler cannot sink the loads back into the loop
#pragma unroll
  for (int m = 0; m < 16; ++m){
    asm volatile("" : "+v"(wg0[m]));
    asm volatile("" : "+v"(wg1[m]));
    asm volatile("" : "+v"(wg2[m]));
    asm volatile("" : "+v"(wg3[m]));
  }
  const float bb = bvec[j + 128*q];   // bias for this thread's gate col

  // branchless activation constants: gate q==2 -> tanh(g)=2*sig(2g)-1, else sigmoid
  const float kexp  = (q == 2) ? -2.88539008f : -1.44269504f;
  const float postm = (q == 2) ? 2.f : 1.f;
  const float posta = (q == 2) ? -1.f : 0.f;

  // ---- state (replicated across the 4 partner lanes) ----
  float cs = c0[b*HID + j];
  float hv = h0[b*HID + j];
  if (q == 0)
    *(u16*)(hbuf[0] + HW_OFF(j)) = __builtin_bit_cast(u16, (f16)hv);
  __syncthreads();

  const u16* xp = xw + (u32)b * G4 + (u32)(j + 128*q);
  float xc  = (float)__builtin_bit_cast(f16, xp[0]) + bb;
  float xn1 = (T_STEPS > 1) ? (float)__builtin_bit_cast(f16, xp[131072u]) + bb : 0.f;

  for (int s = 0; s < T_STEPS; ++s){
    const char* hq = hbuf[s & 1] + q * HQ_STRIDE;

    float xn2 = 0.f;
    if (s + 2 < T_STEPS)
      xn2 = (float)__builtin_bit_cast(f16, xp[(u32)(s+2) * 131072u]) + bb;

    float p0 = 0.f, p1 = 0.f, p2 = 0.f, p3 = 0.f;
#pragma unroll
    for (int it = 0; it < 4; ++it){
      u32x4 hh = *(const u32x4*)(hq + it*16);    // 4 distinct addrs/wave, bank-disjoint
#pragma unroll
      for (int z = 0; z < 4; ++z){
        p0 = dot2f(hh[z], wg0[4*it+z], p0);
        p1 = dot2f(hh[z], wg1[4*it+z], p1);
        p2 = dot2f(hh[z], wg2[4*it+z], p2);
        p3 = dot2f(hh[z], wg3[4*it+z], p3);
      }
    }
    // reduce across the 4 partner lanes (each ends with all-4 totals)
    p0 += __shfl_xor(p0, 1);  p1 += __shfl_xor(p1, 1);
    p2 += __shfl_xor(p2, 1);  p3 += __shfl_xor(p3, 1);
    p0 += __shfl_xor(p0, 2);  p1 += __shfl_xor(p1, 2);
    p2 += __shfl_xor(p2, 2);  p3 += __shfl_xor(p3, 2);

    // this lane activates gate q of col j (branchless: 1 exp + 1 rcp)
    float gsum = (q == 0) ? p0 : (q == 1) ? p1 : (q == 2) ? p2 : p3;
    float gval = gsum + xc;
    float r    = 1.0f / (1.0f + exp2fast(kexp * gval));
    float av   = fmaf(postm, r, posta);

    // gather the 4 activated gates from partner lanes
    float ai = __shfl(av, lbase + 0);
    float af = __shfl(av, lbase + 1);
    float ag = __shfl(av, lbase + 2);
    float ao = __shfl(av, lbase + 3);

    cs = af * cs + ai * ag;
    hv = ao * tanhfast(cs);
    if (q == 0)
      *(u16*)(hbuf[(s & 1) ^ 1] + HW_OFF(j)) = __builtin_bit_cast(u16, (f16)hv);
    __syncthreads();                 // h[s+1] visible; prior-buffer reads all done
    xc = xn1; xn1 = xn2;
  }

  if (q == 0){                       // exact fp32 state out
    out[OUT_HT + b*HID + j] = hv;
    out[OUT_CT + b*HID + j] = cs;
    hf[j] = hv;
  }
  __syncthreads();

  if (t < 256){ // heads hidden, fp32: t<128 -> actor col t; else critic col t-128
    const float* W = (t < HID) ? Wa1 : Wc1;
    const int col  = t & (HID - 1);
    const f32x4* hp4 = (const f32x4*)hf;
    float a0 = 0.f, a1 = 0.f, a2 = 0.f, a3 = 0.f;
#pragma unroll
    for (int qq = 0; qq < 32; ++qq){
      f32x4 hh = hp4[qq];
      a0 = fmaf(hh.x, W[(u32)(4*qq+0)*HID + col], a0);
      a1 = fmaf(hh.y, W[(u32)(4*qq+1)*HID + col], a1);
      a2 = fmaf(hh.z, W[(u32)(4*qq+2)*HID + col], a2);
      a3 = fmaf(hh.w, W[(u32)(4*qq+3)*HID + col], a3);
    }
    float a = (a0 + a1) + (a2 + a3);
    hid[t] = (t < HID) ? tanhfast(a + ba1[col]) : tanhfast(a + bc1[col]);
  }
  __syncthreads();

  {
    const int wv = t >> 6, lane = t & 63;
    float p = 0.f;
    if (wv == 0)      p = hid[lane]     * Wa2[lane*2]   + hid[lane+64]     * Wa2[(lane+64)*2];
    else if (wv == 1) p = hid[lane]     * Wa2[lane*2+1] + hid[lane+64]     * Wa2[(lane+64)*2+1];
    else if (wv == 2) p = hid[128+lane] * Wc2[lane]     + hid[128+lane+64] * Wc2[lane+64];
#pragma unroll
    for (int off = 32; off > 0; off >>= 1) p += __shfl_down(p, off);
    if (lane == 0){
      if (wv == 0) out[b*2 + 0]   = p + ba2[0];
      if (wv == 1) out[b*2 + 1]   = p + ba2[1];
      if (wv == 2) out[OUT_VAL+b] = p + bc2[0];
    }
    if (b == 0 && wv == 3 && lane < 2) out[OUT_STD + lane] = expf(log_std[lane]);
  }
}

extern "C" void kernel_launch(void* const* d_in, const int* in_sizes, int n_in,
                              void* d_out, int out_size, void* d_ws, size_t ws_size,
                              hipStream_t stream)
{
  (void)in_sizes; (void)n_in; (void)out_size; (void)ws_size;
  const float* x    = (const float*)d_in[0];
  const float* h0   = (const float*)d_in[1];
  const float* c0   = (const float*)d_in[2];
  const float* Wx   = (const float*)d_in[3];
  const float* Wh   = (const float*)d_in[4];
  const float* bv   = (const float*)d_in[5];
  const float* Wa1  = (const float*)d_in[6];
  const float* ba1  = (const float*)d_in[7];
  const float* Wa2  = (const float*)d_in[8];
  const float* ba2  = (const float*)d_in[9];
  const float* lstd = (const float*)d_in[10];
  const float* Wc1  = (const float*)d_in[11];
  const float* bc1  = (const float*)d_in[12];
  const float* Wc2  = (const float*)d_in[13];
  const float* bc2  = (const float*)d_in[14];
  float* out = (float*)d_out;
  char*  ws  = (char*)d_ws;

  u16* xw  = (u16*)(ws + XW_OFF);
  u16* wxt = (u16*)(ws + WXT_OFF);

  k_pack_wxt<<<dim3(512),  dim3(256), 0, stream>>>(Wx, wxt);
  k_gemm<<<dim3(2048),     dim3(256), 0, stream>>>(x, wxt, xw);
  k_rnn<<<dim3(256),       dim3(512), 0, stream>>>(xw, Wh, h0, c0, bv,
                                                   Wa1, ba1, Wa2, ba2, Wc1, bc1, Wc2, bc2,
                                                   lstd, out);
}

// Round 10
// 755.604 us; speedup vs baseline: 1.5286x; 1.0912x over previous
//
#include <hip/hip_runtime.h>
#include <hip/hip_bf16.h>

typedef unsigned int   u32;
typedef unsigned short u16;
typedef _Float16       f16;
typedef __attribute__((ext_vector_type(2))) _Float16 f16x2;
typedef __attribute__((ext_vector_type(8))) _Float16 f16x8;
typedef __attribute__((ext_vector_type(4))) float    f32x4;
typedef __attribute__((ext_vector_type(4))) u32      u32x4;

#define T_STEPS 512
#define BATCH   256
#define O_IN    720
#define KPAD    736      // 720 padded to mult of 32 (zero pad in wxt)
#define HID     128
#define G4      512      // 4*HID
// d_out layout (floats): am[512] | std[2] | value[256] | hT[32768] | cT[32768]
#define OUT_STD 512
#define OUT_VAL 514
#define OUT_HT  770
#define OUT_CT  33538

// ws layout (bytes); requires ws_size >= ~135 MB
static const unsigned long long XW_OFF  = 0ull;          // f16 [131072][512] = 134217728 B
static const unsigned long long WXT_OFF = 134217728ull;  // f16 [512][736]    = 753664 B

__device__ inline float exp2fast(float x){
#if __has_builtin(__builtin_amdgcn_exp2f)
  return __builtin_amdgcn_exp2f(x);
#else
  return exp2f(x);
#endif
}
__device__ inline float sigf(float x){ return 1.0f / (1.0f + exp2fast(-1.44269504f * x)); }
__device__ inline float tanhfast(float x){ return 2.0f / (1.0f + exp2fast(-2.88539008f * x)) - 1.0f; }

// d = a.lo*b.lo + a.hi*b.hi + c  (f16 pairs, f32 accum) — inline asm (builtin is broken:
// R2/R8 bit-identical failures; asm validated in R9, absmax 0.0078).
__device__ inline float dot2f(u32 a, u32 b, float c){
  float d;
  asm("v_dot2_f32_f16 %0, %1, %2, %3" : "=v"(d) : "v"(a), "v"(b), "v"(c));
  return d;
}

// DPP quad_perm cross-lane (VALU pipe — replaces ds_swizzle-based __shfl, off the DS unit).
// ctrl: [a,b,c,d] -> a|b<<2|c<<4|d<<6. xor1=[1,0,3,2]=177, xor2=[2,3,0,1]=78,
// bcast0..3 = 0,85,170,255.
#define DPPF(x, ctrl) \
  __uint_as_float((u32)__builtin_amdgcn_update_dpp(0, (int)__float_as_uint(x), (ctrl), 0xF, 0xF, false))

// h stored as f16 in LDS. Quarter q (32 halves = 64B) at byte q*80 (16B pad/quarter):
// 16B-aligned for ds_read_b128; 4 wave-simultaneous quarter addresses are bank-disjoint.
#define HQ_STRIDE 80
#define H_BYTES   (4*HQ_STRIDE)
#define HW_OFF(j) (((j)>>5)*HQ_STRIDE + ((j)&31)*2)

// ---------------- K0: Wx (720,512) f32 -> Wx^T f16 [512][736] zero-padded ----------------
__global__ void k_pack_wxt(const float* __restrict__ Wx, u16* __restrict__ wxt){
  const int n = blockIdx.x;               // 512 blocks
  for (int k = threadIdx.x; k < KPAD; k += 256){
    float v = (k < O_IN) ? Wx[(size_t)k * G4 + n] : 0.f;
    wxt[(size_t)n * KPAD + k] = __builtin_bit_cast(u16, (f16)v);
  }
}

// ---------------- K1: xW = x @ Wx  (fp16 MFMA, LDS-free, no barriers) --------------------
// Unchanged (validated; outputs pass through it).
__global__ __launch_bounds__(256, 2) void k_gemm(const float* __restrict__ x,
                                                 const u16* __restrict__ wxt,
                                                 u16* __restrict__ xw)
{
  const int l  = threadIdx.x & 63;
  const int w  = threadIdx.x >> 6;
  const int lr = l & 15;
  const int lk = l >> 4;
  const u32 L  = (blockIdx.x & 7u) * 256u + (blockIdx.x >> 3);
  const u32 mb = L >> 2, nb = L & 3u;
  const u32 M0 = mb * 256u + (u32)w * 64u;
  const u32 N0 = nb * 128u;

  const float* ax[4];
  const u16*   bx[8];
#pragma unroll
  for (int mf = 0; mf < 4; ++mf)
    ax[mf] = x + (unsigned long long)(M0 + mf*16 + lr) * O_IN + lk*8;
#pragma unroll
  for (int nf = 0; nf < 8; ++nf)
    bx[nf] = wxt + (unsigned long long)(N0 + nf*16 + lr) * KPAD + lk*8;

  f32x4 acc[4][8];
#pragma unroll
  for (int mf = 0; mf < 4; ++mf)
#pragma unroll
    for (int nf = 0; nf < 8; ++nf)
      acc[mf][nf] = (f32x4){0.f, 0.f, 0.f, 0.f};

  f32x4 a0[4][2];
  f16x8 aF[4], bF[8];

#pragma unroll
  for (int mf = 0; mf < 4; ++mf){
    a0[mf][0] = *(const f32x4*)(ax[mf]);
    a0[mf][1] = *(const f32x4*)(ax[mf] + 4);
  }
#pragma unroll
  for (int nf = 0; nf < 8; ++nf)
    bF[nf] = *(const f16x8*)(bx[nf]);
#pragma unroll
  for (int mf = 0; mf < 4; ++mf){
    f32x4 lo = a0[mf][0], hi = a0[mf][1];
    f16x8 v; v[0]=(f16)lo.x; v[1]=(f16)lo.y; v[2]=(f16)lo.z; v[3]=(f16)lo.w;
             v[4]=(f16)hi.x; v[5]=(f16)hi.y; v[6]=(f16)hi.z; v[7]=(f16)hi.w;
    aF[mf] = v;
  }

  for (int kc = 0; kc < 22; ++kc){
    if (kc < 21){
#pragma unroll
      for (int mf = 0; mf < 4; ++mf){
        a0[mf][0] = *(const f32x4*)(ax[mf] + (kc+1)*32);
        a0[mf][1] = *(const f32x4*)(ax[mf] + (kc+1)*32 + 4);
      }
    }
#pragma unroll
    for (int nf = 0; nf < 8; ++nf){
#pragma unroll
      for (int mf = 0; mf < 4; ++mf)
        acc[mf][nf] = __builtin_amdgcn_mfma_f32_16x16x32_f16(aF[mf], bF[nf], acc[mf][nf], 0, 0, 0);
      if (kc < 21)
        bF[nf] = *(const f16x8*)(bx[nf] + (kc+1)*32);
    }
    if (kc < 21){
#pragma unroll
      for (int mf = 0; mf < 4; ++mf){
        f32x4 lo = a0[mf][0], hi = a0[mf][1];
        f16x8 v; v[0]=(f16)lo.x; v[1]=(f16)lo.y; v[2]=(f16)lo.z; v[3]=(f16)lo.w;
                 v[4]=(f16)hi.x; v[5]=(f16)hi.y; v[6]=(f16)hi.z; v[7]=(f16)hi.w;
        aF[mf] = v;
      }
    }
  }

  {
    f16x8 aT[4];
#pragma unroll
    for (int mf = 0; mf < 4; ++mf) aT[mf] = (f16x8)(f16)0.f;
    if (lk < 2){
#pragma unroll
      for (int mf = 0; mf < 4; ++mf){
        f32x4 lo = *(const f32x4*)(ax[mf] + 704);
        f32x4 hi = *(const f32x4*)(ax[mf] + 708);
        f16x8 v; v[0]=(f16)lo.x; v[1]=(f16)lo.y; v[2]=(f16)lo.z; v[3]=(f16)lo.w;
                 v[4]=(f16)hi.x; v[5]=(f16)hi.y; v[6]=(f16)hi.z; v[7]=(f16)hi.w;
        aT[mf] = v;
      }
    }
#pragma unroll
    for (int nf = 0; nf < 8; ++nf){
      f16x8 bT = *(const f16x8*)(bx[nf] + 704);
#pragma unroll
      for (int mf = 0; mf < 4; ++mf)
        acc[mf][nf] = __builtin_amdgcn_mfma_f32_16x16x32_f16(aT[mf], bT, acc[mf][nf], 0, 0, 0);
    }
  }

#pragma unroll
  for (int mf = 0; mf < 4; ++mf){
    const u32 rowb = M0 + mf*16 + lk*4;
#pragma unroll
    for (int nf = 0; nf < 8; ++nf){
      const u32 col = N0 + nf*16 + lr;
#pragma unroll
      for (int r = 0; r < 4; ++r)
        xw[(unsigned long long)(rowb + r) * G4 + col] = __builtin_bit_cast(u16, (f16)acc[mf][nf][r]);
    }
  }
}

// ---------------- K2: LSTM scan, f16 dot2 + DPP reduce (1 row/CU, 512 thr) ----------------
// waves_per_eu(2,2): allocator budget 256 VGPR, no occupancy-chasing -> 64 weight regs
// stay RESIDENT (R6-R9: VGPR pinned at 64/84/96 => spill/sink, 2700 cyc/step).
// Cross-lane via DPP quad_perm (VALU) instead of __shfl (ds_swizzle, DS pipe).
__global__ __attribute__((amdgpu_flat_work_group_size(512,512), amdgpu_waves_per_eu(2,2)))
void k_rnn(
    const u16* __restrict__ xw, const float* __restrict__ Wh,
    const float* __restrict__ h0, const float* __restrict__ c0,
    const float* __restrict__ bvec,
    const float* __restrict__ Wa1, const float* __restrict__ ba1,
    const float* __restrict__ Wa2, const float* __restrict__ ba2,
    const float* __restrict__ Wc1, const float* __restrict__ bc1,
    const float* __restrict__ Wc2, const float* __restrict__ bc2,
    const float* __restrict__ log_std, float* __restrict__ out)
{
  const int b = blockIdx.x;
  const int t = threadIdx.x;          // 0..511
  const int j = t >> 2;               // gate/h column 0..127
  const int q = t & 3;                // k-quarter & gate slot

  __shared__ __align__(16) char hbuf[2][H_BYTES];  // h f16, padded quarters, double-buffered
  __shared__ __align__(16) float hf[HID];          // final h fp32 (heads)
  __shared__ float hid[256];

  // ---- weights: wgN[m] = f16x2{ Wh[32q+2m][j+128N], Wh[32q+2m+1][j+128N] } ----
  u32 wg0[16], wg1[16], wg2[16], wg3[16];
#pragma unroll
  for (int m = 0; m < 16; ++m){
    const u32 kb = (u32)(32*q + 2*m) * G4 + (u32)j;
    f16x2 p;
    p[0]=(f16)Wh[kb      ]; p[1]=(f16)Wh[kb+G4      ]; wg0[m]=__builtin_bit_cast(u32,p);
    p[0]=(f16)Wh[kb+128  ]; p[1]=(f16)Wh[kb+G4+128  ]; wg1[m]=__builtin_bit_cast(u32,p);
    p[0]=(f16)Wh[kb+256  ]; p[1]=(f16)Wh[kb+G4+256  ]; wg2[m]=__builtin_bit_cast(u32,p);
    p[0]=(f16)Wh[kb+384  ]; p[1]=(f16)Wh[kb+G4+384  ]; wg3[m]=__builtin_bit_cast(u32,p);
  }
  // pin: opaque identity so the scheduler cannot sink the loads back into the loop
#pragma unroll
  for (int m = 0; m < 16; ++m){
    asm volatile("" : "+v"(wg0[m]));
    asm volatile("" : "+v"(wg1[m]));
    asm volatile("" : "+v"(wg2[m]));
    asm volatile("" : "+v"(wg3[m]));
  }
  const float bb = bvec[j + 128*q];   // bias for this thread's gate col

  // branchless activation constants: gate q==2 -> tanh(g)=2*sig(2g)-1, else sigmoid
  const float kexp  = (q == 2) ? -2.88539008f : -1.44269504f;
  const float postm = (q == 2) ? 2.f : 1.f;
  const float posta = (q == 2) ? -1.f : 0.f;

  // ---- state (replicated across the 4 partner lanes) ----
  float cs = c0[b*HID + j];
  float hv = h0[b*HID + j];
  if (q == 0)
    *(u16*)(hbuf[0] + HW_OFF(j)) = __builtin_bit_cast(u16, (f16)hv);
  __syncthreads();

  const u16* xp = xw + (u32)b * G4 + (u32)(j + 128*q);
  float xc  = (float)__builtin_bit_cast(f16, xp[0]) + bb;
  float xn1 = (T_STEPS > 1) ? (float)__builtin_bit_cast(f16, xp[131072u]) + bb : 0.f;

  for (int s = 0; s < T_STEPS; ++s){
    const char* hq = hbuf[s & 1] + q * HQ_STRIDE;

    float xn2 = 0.f;
    if (s + 2 < T_STEPS)
      xn2 = (float)__builtin_bit_cast(f16, xp[(u32)(s+2) * 131072u]) + bb;

    float p0 = 0.f, p1 = 0.f, p2 = 0.f, p3 = 0.f;
#pragma unroll
    for (int it = 0; it < 4; ++it){
      u32x4 hh = *(const u32x4*)(hq + it*16);    // 4 distinct addrs/wave, bank-disjoint
#pragma unroll
      for (int z = 0; z < 4; ++z){
        p0 = dot2f(hh[z], wg0[4*it+z], p0);
        p1 = dot2f(hh[z], wg1[4*it+z], p1);
        p2 = dot2f(hh[z], wg2[4*it+z], p2);
        p3 = dot2f(hh[z], wg3[4*it+z], p3);
      }
    }
    // reduce across the 4 partner lanes via DPP quad_perm (VALU, no DS traffic)
    p0 += DPPF(p0, 177);  p1 += DPPF(p1, 177);   // xor 1
    p2 += DPPF(p2, 177);  p3 += DPPF(p3, 177);
    p0 += DPPF(p0, 78);   p1 += DPPF(p1, 78);    // xor 2
    p2 += DPPF(p2, 78);   p3 += DPPF(p3, 78);

    // this lane activates gate q of col j (branchless: 1 exp + 1 rcp)
    float gsum = (q == 0) ? p0 : (q == 1) ? p1 : (q == 2) ? p2 : p3;
    float gval = gsum + xc;
    float r    = 1.0f / (1.0f + exp2fast(kexp * gval));
    float av   = fmaf(postm, r, posta);

    // gather the 4 activated gates from partner lanes (DPP quad broadcasts)
    float ai = DPPF(av, 0);     // lane lbase+0
    float af = DPPF(av, 85);    // lane lbase+1
    float ag = DPPF(av, 170);   // lane lbase+2
    float ao = DPPF(av, 255);   // lane lbase+3

    cs = af * cs + ai * ag;
    hv = ao * tanhfast(cs);
    if (q == 0)
      *(u16*)(hbuf[(s & 1) ^ 1] + HW_OFF(j)) = __builtin_bit_cast(u16, (f16)hv);
    __syncthreads();                 // h[s+1] visible; prior-buffer reads all done
    xc = xn1; xn1 = xn2;
  }

  if (q == 0){                       // exact fp32 state out
    out[OUT_HT + b*HID + j] = hv;
    out[OUT_CT + b*HID + j] = cs;
    hf[j] = hv;
  }
  __syncthreads();

  if (t < 256){ // heads hidden, fp32: t<128 -> actor col t; else critic col t-128
    const float* W = (t < HID) ? Wa1 : Wc1;
    const int col  = t & (HID - 1);
    const f32x4* hp4 = (const f32x4*)hf;
    float a0 = 0.f, a1 = 0.f, a2 = 0.f, a3 = 0.f;
#pragma unroll
    for (int qq = 0; qq < 32; ++qq){
      f32x4 hh = hp4[qq];
      a0 = fmaf(hh.x, W[(u32)(4*qq+0)*HID + col], a0);
      a1 = fmaf(hh.y, W[(u32)(4*qq+1)*HID + col], a1);
      a2 = fmaf(hh.z, W[(u32)(4*qq+2)*HID + col], a2);
      a3 = fmaf(hh.w, W[(u32)(4*qq+3)*HID + col], a3);
    }
    float a = (a0 + a1) + (a2 + a3);
    hid[t] = (t < HID) ? tanhfast(a + ba1[col]) : tanhfast(a + bc1[col]);
  }
  __syncthreads();

  {
    const int wv = t >> 6, lane = t & 63;
    float p = 0.f;
    if (wv == 0)      p = hid[lane]     * Wa2[lane*2]   + hid[lane+64]     * Wa2[(lane+64)*2];
    else if (wv == 1) p = hid[lane]     * Wa2[lane*2+1] + hid[lane+64]     * Wa2[(lane+64)*2+1];
    else if (wv == 2) p = hid[128+lane] * Wc2[lane]     + hid[128+lane+64] * Wc2[lane+64];
#pragma unroll
    for (int off = 32; off > 0; off >>= 1) p += __shfl_down(p, off);
    if (lane == 0){
      if (wv == 0) out[b*2 + 0]   = p + ba2[0];
      if (wv == 1) out[b*2 + 1]   = p + ba2[1];
      if (wv == 2) out[OUT_VAL+b] = p + bc2[0];
    }
    if (b == 0 && wv == 3 && lane < 2) out[OUT_STD + lane] = expf(log_std[lane]);
  }
}

extern "C" void kernel_launch(void* const* d_in, const int* in_sizes, int n_in,
                              void* d_out, int out_size, void* d_ws, size_t ws_size,
                              hipStream_t stream)
{
  (void)in_sizes; (void)n_in; (void)out_size; (void)ws_size;
  const float* x    = (const float*)d_in[0];
  const float* h0   = (const float*)d_in[1];
  const float* c0   = (const float*)d_in[2];
  const float* Wx   = (const float*)d_in[3];
  const float* Wh   = (const float*)d_in[4];
  const float* bv   = (const float*)d_in[5];
  const float* Wa1  = (const float*)d_in[6];
  const float* ba1  = (const float*)d_in[7];
  const float* Wa2  = (const float*)d_in[8];
  const float* ba2  = (const float*)d_in[9];
  const float* lstd = (const float*)d_in[10];
  const float* Wc1  = (const float*)d_in[11];
  const float* bc1  = (const float*)d_in[12];
  const float* Wc2  = (const float*)d_in[13];
  const float* bc2  = (const float*)d_in[14];
  float* out = (float*)d_out;
  char*  ws  = (char*)d_ws;

  u16* xw  = (u16*)(ws + XW_OFF);
  u16* wxt = (u16*)(ws + WXT_OFF);

  k_pack_wxt<<<dim3(512),  dim3(256), 0, stream>>>(Wx, wxt);
  k_gemm<<<dim3(2048),     dim3(256), 0, stream>>>(x, wxt, xw);
  k_rnn<<<dim3(256),       dim3(512), 0, stream>>>(xw, Wh, h0, c0, bv,
                                                   Wa1, ba1, Wa2, ba2, Wc1, bc1, Wc2, bc2,
                                                   lstd, out);
}

// Round 11
// 722.767 us; speedup vs baseline: 1.5980x; 1.0454x over previous
//
#include <hip/hip_runtime.h>
#include <hip/hip_bf16.h>

typedef unsigned int   u32;
typedef unsigned short u16;
typedef _Float16       f16;
typedef __attribute__((ext_vector_type(2))) _Float16 f16x2;
typedef __attribute__((ext_vector_type(8))) _Float16 f16x8;
typedef __attribute__((ext_vector_type(4))) float    f32x4;
typedef __attribute__((ext_vector_type(4))) u32      u32x4;

#define T_STEPS 512
#define BATCH   256
#define O_IN    720
#define KPAD    736      // 720 padded to mult of 32 (zero pad in wxt)
#define HID     128
#define G4      512      // 4*HID
// d_out layout (floats): am[512] | std[2] | value[256] | hT[32768] | cT[32768]
#define OUT_STD 512
#define OUT_VAL 514
#define OUT_HT  770
#define OUT_CT  33538

// ws layout (bytes); requires ws_size >= ~135 MB
static const unsigned long long XW_OFF  = 0ull;          // f16 [131072][512] = 134217728 B
static const unsigned long long WXT_OFF = 134217728ull;  // f16 [512][736]    = 753664 B

// raw transcendental asm: v_exp_f32 computes 2^x (1 trans op); v_rcp_f32 ~1ulp.
// Replaces precise-path exp2f + full-division sequences (~150 VALU/step, the R10 wall).
__device__ inline float exp2raw(float x){
  float r; asm("v_exp_f32 %0, %1" : "=v"(r) : "v"(x)); return r;
}
__device__ inline float rcpraw(float x){
  float r; asm("v_rcp_f32 %0, %1" : "=v"(r) : "v"(x)); return r;
}
__device__ inline float sigf(float x){ return rcpraw(1.0f + exp2raw(-1.44269504f * x)); }
__device__ inline float tanhfast(float x){
  return fmaf(2.f, rcpraw(1.0f + exp2raw(-2.88539008f * x)), -1.f);
}

// d = a.lo*b.lo + a.hi*b.hi + c  (f16 pairs, f32 accum) — inline asm (builtin is broken:
// R2/R8 bit-identical failures; asm validated in R9, absmax 0.0078).
__device__ inline float dot2f(u32 a, u32 b, float c){
  float d;
  asm("v_dot2_f32_f16 %0, %1, %2, %3" : "=v"(d) : "v"(a), "v"(b), "v"(c));
  return d;
}

// DPP quad_perm cross-lane (VALU pipe). ctrl: [a,b,c,d] -> a|b<<2|c<<4|d<<6.
// xor1=177, xor2=78, bcast0..3 = 0,85,170,255.
#define DPPF(x, ctrl) \
  __uint_as_float((u32)__builtin_amdgcn_update_dpp(0, (int)__float_as_uint(x), (ctrl), 0xF, 0xF, false))

// h stored as f16 in LDS. Quarter q (32 halves = 64B) at byte q*80 (16B pad/quarter):
// 16B-aligned for ds_read_b128; 4 wave-simultaneous quarter addresses are bank-disjoint.
#define HQ_STRIDE 80
#define H_BYTES   (4*HQ_STRIDE)
#define HW_OFF(j) (((j)>>5)*HQ_STRIDE + ((j)&31)*2)

// ---------------- K0: Wx (720,512) f32 -> Wx^T f16 [512][736] zero-padded ----------------
__global__ void k_pack_wxt(const float* __restrict__ Wx, u16* __restrict__ wxt){
  const int n = blockIdx.x;               // 512 blocks
  for (int k = threadIdx.x; k < KPAD; k += 256){
    float v = (k < O_IN) ? Wx[(size_t)k * G4 + n] : 0.f;
    wxt[(size_t)n * KPAD + k] = __builtin_bit_cast(u16, (f16)v);
  }
}

// ---------------- K1: xW = x @ Wx  (fp16 MFMA, LDS-free, no barriers) --------------------
// Unchanged (validated; outputs pass through it).
__global__ __launch_bounds__(256, 2) void k_gemm(const float* __restrict__ x,
                                                 const u16* __restrict__ wxt,
                                                 u16* __restrict__ xw)
{
  const int l  = threadIdx.x & 63;
  const int w  = threadIdx.x >> 6;
  const int lr = l & 15;
  const int lk = l >> 4;
  const u32 L  = (blockIdx.x & 7u) * 256u + (blockIdx.x >> 3);
  const u32 mb = L >> 2, nb = L & 3u;
  const u32 M0 = mb * 256u + (u32)w * 64u;
  const u32 N0 = nb * 128u;

  const float* ax[4];
  const u16*   bx[8];
#pragma unroll
  for (int mf = 0; mf < 4; ++mf)
    ax[mf] = x + (unsigned long long)(M0 + mf*16 + lr) * O_IN + lk*8;
#pragma unroll
  for (int nf = 0; nf < 8; ++nf)
    bx[nf] = wxt + (unsigned long long)(N0 + nf*16 + lr) * KPAD + lk*8;

  f32x4 acc[4][8];
#pragma unroll
  for (int mf = 0; mf < 4; ++mf)
#pragma unroll
    for (int nf = 0; nf < 8; ++nf)
      acc[mf][nf] = (f32x4){0.f, 0.f, 0.f, 0.f};

  f32x4 a0[4][2];
  f16x8 aF[4], bF[8];

#pragma unroll
  for (int mf = 0; mf < 4; ++mf){
    a0[mf][0] = *(const f32x4*)(ax[mf]);
    a0[mf][1] = *(const f32x4*)(ax[mf] + 4);
  }
#pragma unroll
  for (int nf = 0; nf < 8; ++nf)
    bF[nf] = *(const f16x8*)(bx[nf]);
#pragma unroll
  for (int mf = 0; mf < 4; ++mf){
    f32x4 lo = a0[mf][0], hi = a0[mf][1];
    f16x8 v; v[0]=(f16)lo.x; v[1]=(f16)lo.y; v[2]=(f16)lo.z; v[3]=(f16)lo.w;
             v[4]=(f16)hi.x; v[5]=(f16)hi.y; v[6]=(f16)hi.z; v[7]=(f16)hi.w;
    aF[mf] = v;
  }

  for (int kc = 0; kc < 22; ++kc){
    if (kc < 21){
#pragma unroll
      for (int mf = 0; mf < 4; ++mf){
        a0[mf][0] = *(const f32x4*)(ax[mf] + (kc+1)*32);
        a0[mf][1] = *(const f32x4*)(ax[mf] + (kc+1)*32 + 4);
      }
    }
#pragma unroll
    for (int nf = 0; nf < 8; ++nf){
#pragma unroll
      for (int mf = 0; mf < 4; ++mf)
        acc[mf][nf] = __builtin_amdgcn_mfma_f32_16x16x32_f16(aF[mf], bF[nf], acc[mf][nf], 0, 0, 0);
      if (kc < 21)
        bF[nf] = *(const f16x8*)(bx[nf] + (kc+1)*32);
    }
    if (kc < 21){
#pragma unroll
      for (int mf = 0; mf < 4; ++mf){
        f32x4 lo = a0[mf][0], hi = a0[mf][1];
        f16x8 v; v[0]=(f16)lo.x; v[1]=(f16)lo.y; v[2]=(f16)lo.z; v[3]=(f16)lo.w;
                 v[4]=(f16)hi.x; v[5]=(f16)hi.y; v[6]=(f16)hi.z; v[7]=(f16)hi.w;
        aF[mf] = v;
      }
    }
  }

  {
    f16x8 aT[4];
#pragma unroll
    for (int mf = 0; mf < 4; ++mf) aT[mf] = (f16x8)(f16)0.f;
    if (lk < 2){
#pragma unroll
      for (int mf = 0; mf < 4; ++mf){
        f32x4 lo = *(const f32x4*)(ax[mf] + 704);
        f32x4 hi = *(const f32x4*)(ax[mf] + 708);
        f16x8 v; v[0]=(f16)lo.x; v[1]=(f16)lo.y; v[2]=(f16)lo.z; v[3]=(f16)lo.w;
                 v[4]=(f16)hi.x; v[5]=(f16)hi.y; v[6]=(f16)hi.z; v[7]=(f16)hi.w;
        aT[mf] = v;
      }
    }
#pragma unroll
    for (int nf = 0; nf < 8; ++nf){
      f16x8 bT = *(const f16x8*)(bx[nf] + 704);
#pragma unroll
      for (int mf = 0; mf < 4; ++mf)
        acc[mf][nf] = __builtin_amdgcn_mfma_f32_16x16x32_f16(aT[mf], bT, acc[mf][nf], 0, 0, 0);
    }
  }

#pragma unroll
  for (int mf = 0; mf < 4; ++mf){
    const u32 rowb = M0 + mf*16 + lk*4;
#pragma unroll
    for (int nf = 0; nf < 8; ++nf){
      const u32 col = N0 + nf*16 + lr;
#pragma unroll
      for (int r = 0; r < 4; ++r)
        xw[(unsigned long long)(rowb + r) * G4 + col] = __builtin_bit_cast(u16, (f16)acc[mf][nf][r]);
    }
  }
}

// ---------------- K2: LSTM scan, f16 dot2 + DPP reduce + raw transcendentals --------------
// waves_per_eu(2,2): 256-VGPR budget, weights resident (R10: VGPR 88, no spill).
// R11: v_exp_f32/v_rcp_f32 asm replaces precise exp2f + full divisions (~200 VALU/step).
__global__ __attribute__((amdgpu_flat_work_group_size(512,512), amdgpu_waves_per_eu(2,2)))
void k_rnn(
    const u16* __restrict__ xw, const float* __restrict__ Wh,
    const float* __restrict__ h0, const float* __restrict__ c0,
    const float* __restrict__ bvec,
    const float* __restrict__ Wa1, const float* __restrict__ ba1,
    const float* __restrict__ Wa2, const float* __restrict__ ba2,
    const float* __restrict__ Wc1, const float* __restrict__ bc1,
    const float* __restrict__ Wc2, const float* __restrict__ bc2,
    const float* __restrict__ log_std, float* __restrict__ out)
{
  const int b = blockIdx.x;
  const int t = threadIdx.x;          // 0..511
  const int j = t >> 2;               // gate/h column 0..127
  const int q = t & 3;                // k-quarter & gate slot

  __shared__ __align__(16) char hbuf[2][H_BYTES];  // h f16, padded quarters, double-buffered
  __shared__ __align__(16) float hf[HID];          // final h fp32 (heads)
  __shared__ float hid[256];

  // ---- weights: wgN[m] = f16x2{ Wh[32q+2m][j+128N], Wh[32q+2m+1][j+128N] } ----
  u32 wg0[16], wg1[16], wg2[16], wg3[16];
#pragma unroll
  for (int m = 0; m < 16; ++m){
    const u32 kb = (u32)(32*q + 2*m) * G4 + (u32)j;
    f16x2 p;
    p[0]=(f16)Wh[kb      ]; p[1]=(f16)Wh[kb+G4      ]; wg0[m]=__builtin_bit_cast(u32,p);
    p[0]=(f16)Wh[kb+128  ]; p[1]=(f16)Wh[kb+G4+128  ]; wg1[m]=__builtin_bit_cast(u32,p);
    p[0]=(f16)Wh[kb+256  ]; p[1]=(f16)Wh[kb+G4+256  ]; wg2[m]=__builtin_bit_cast(u32,p);
    p[0]=(f16)Wh[kb+384  ]; p[1]=(f16)Wh[kb+G4+384  ]; wg3[m]=__builtin_bit_cast(u32,p);
  }
  // pin: opaque identity so the scheduler cannot sink the loads back into the loop
#pragma unroll
  for (int m = 0; m < 16; ++m){
    asm volatile("" : "+v"(wg0[m]));
    asm volatile("" : "+v"(wg1[m]));
    asm volatile("" : "+v"(wg2[m]));
    asm volatile("" : "+v"(wg3[m]));
  }
  const float bb = bvec[j + 128*q];   // bias for this thread's gate col

  // branchless activation constants: gate q==2 -> tanh(g)=2*sig(2g)-1, else sigmoid
  const float kexp  = (q == 2) ? -2.88539008f : -1.44269504f;
  const float postm = (q == 2) ? 2.f : 1.f;
  const float posta = (q == 2) ? -1.f : 0.f;

  // ---- state (replicated across the 4 partner lanes) ----
  float cs = c0[b*HID + j];
  float hv = h0[b*HID + j];
  if (q == 0)
    *(u16*)(hbuf[0] + HW_OFF(j)) = __builtin_bit_cast(u16, (f16)hv);
  __syncthreads();

  const u16* xp = xw + (u32)b * G4 + (u32)(j + 128*q);
  float xc  = (float)__builtin_bit_cast(f16, xp[0]) + bb;
  float xn1 = (T_STEPS > 1) ? (float)__builtin_bit_cast(f16, xp[131072u]) + bb : 0.f;

  for (int s = 0; s < T_STEPS; ++s){
    const char* hq = hbuf[s & 1] + q * HQ_STRIDE;

    float xn2 = 0.f;
    if (s + 2 < T_STEPS)
      xn2 = (float)__builtin_bit_cast(f16, xp[(u32)(s+2) * 131072u]) + bb;

    float p0 = 0.f, p1 = 0.f, p2 = 0.f, p3 = 0.f;
#pragma unroll
    for (int it = 0; it < 4; ++it){
      u32x4 hh = *(const u32x4*)(hq + it*16);    // 4 distinct addrs/wave, bank-disjoint
#pragma unroll
      for (int z = 0; z < 4; ++z){
        p0 = dot2f(hh[z], wg0[4*it+z], p0);
        p1 = dot2f(hh[z], wg1[4*it+z], p1);
        p2 = dot2f(hh[z], wg2[4*it+z], p2);
        p3 = dot2f(hh[z], wg3[4*it+z], p3);
      }
    }
    // reduce across the 4 partner lanes via DPP quad_perm (VALU, no DS traffic)
    p0 += DPPF(p0, 177);  p1 += DPPF(p1, 177);   // xor 1
    p2 += DPPF(p2, 177);  p3 += DPPF(p3, 177);
    p0 += DPPF(p0, 78);   p1 += DPPF(p1, 78);    // xor 2
    p2 += DPPF(p2, 78);   p3 += DPPF(p3, 78);

    // this lane activates gate q of col j: mul -> exp -> add -> rcp -> fma (5 insts)
    float gsum = (q == 0) ? p0 : (q == 1) ? p1 : (q == 2) ? p2 : p3;
    float gval = gsum + xc;
    float r    = rcpraw(1.0f + exp2raw(kexp * gval));
    float av   = fmaf(postm, r, posta);

    // gather the 4 activated gates from partner lanes (DPP quad broadcasts)
    float ai = DPPF(av, 0);     // lane lbase+0
    float af = DPPF(av, 85);    // lane lbase+1
    float ag = DPPF(av, 170);   // lane lbase+2
    float ao = DPPF(av, 255);   // lane lbase+3

    cs = af * cs + ai * ag;
    hv = ao * tanhfast(cs);
    if (q == 0)
      *(u16*)(hbuf[(s & 1) ^ 1] + HW_OFF(j)) = __builtin_bit_cast(u16, (f16)hv);
    __syncthreads();                 // h[s+1] visible; prior-buffer reads all done
    xc = xn1; xn1 = xn2;
  }

  if (q == 0){                       // exact fp32 state out
    out[OUT_HT + b*HID + j] = hv;
    out[OUT_CT + b*HID + j] = cs;
    hf[j] = hv;
  }
  __syncthreads();

  if (t < 256){ // heads hidden, fp32: t<128 -> actor col t; else critic col t-128
    const float* W = (t < HID) ? Wa1 : Wc1;
    const int col  = t & (HID - 1);
    const f32x4* hp4 = (const f32x4*)hf;
    float a0 = 0.f, a1 = 0.f, a2 = 0.f, a3 = 0.f;
#pragma unroll
    for (int qq = 0; qq < 32; ++qq){
      f32x4 hh = hp4[qq];
      a0 = fmaf(hh.x, W[(u32)(4*qq+0)*HID + col], a0);
      a1 = fmaf(hh.y, W[(u32)(4*qq+1)*HID + col], a1);
      a2 = fmaf(hh.z, W[(u32)(4*qq+2)*HID + col], a2);
      a3 = fmaf(hh.w, W[(u32)(4*qq+3)*HID + col], a3);
    }
    float a = (a0 + a1) + (a2 + a3);
    hid[t] = (t < HID) ? tanhfast(a + ba1[col]) : tanhfast(a + bc1[col]);
  }
  __syncthreads();

  {
    const int wv = t >> 6, lane = t & 63;
    float p = 0.f;
    if (wv == 0)      p = hid[lane]     * Wa2[lane*2]   + hid[lane+64]     * Wa2[(lane+64)*2];
    else if (wv == 1) p = hid[lane]     * Wa2[lane*2+1] + hid[lane+64]     * Wa2[(lane+64)*2+1];
    else if (wv == 2) p = hid[128+lane] * Wc2[lane]     + hid[128+lane+64] * Wc2[lane+64];
#pragma unroll
    for (int off = 32; off > 0; off >>= 1) p += __shfl_down(p, off);
    if (lane == 0){
      if (wv == 0) out[b*2 + 0]   = p + ba2[0];
      if (wv == 1) out[b*2 + 1]   = p + ba2[1];
      if (wv == 2) out[OUT_VAL+b] = p + bc2[0];
    }
    if (b == 0 && wv == 3 && lane < 2) out[OUT_STD + lane] = expf(log_std[lane]);
  }
}

extern "C" void kernel_launch(void* const* d_in, const int* in_sizes, int n_in,
                              void* d_out, int out_size, void* d_ws, size_t ws_size,
                              hipStream_t stream)
{
  (void)in_sizes; (void)n_in; (void)out_size; (void)ws_size;
  const float* x    = (const float*)d_in[0];
  const float* h0   = (const float*)d_in[1];
  const float* c0   = (const float*)d_in[2];
  const float* Wx   = (const float*)d_in[3];
  const float* Wh   = (const float*)d_in[4];
  const float* bv   = (const float*)d_in[5];
  const float* Wa1  = (const float*)d_in[6];
  const float* ba1  = (const float*)d_in[7];
  const float* Wa2  = (const float*)d_in[8];
  const float* ba2  = (const float*)d_in[9];
  const float* lstd = (const float*)d_in[10];
  const float* Wc1  = (const float*)d_in[11];
  const float* bc1  = (const float*)d_in[12];
  const float* Wc2  = (const float*)d_in[13];
  const float* bc2  = (const float*)d_in[14];
  float* out = (float*)d_out;
  char*  ws  = (char*)d_ws;

  u16* xw  = (u16*)(ws + XW_OFF);
  u16* wxt = (u16*)(ws + WXT_OFF);

  k_pack_wxt<<<dim3(512),  dim3(256), 0, stream>>>(Wx, wxt);
  k_gemm<<<dim3(2048),     dim3(256), 0, stream>>>(x, wxt, xw);
  k_rnn<<<dim3(256),       dim3(512), 0, stream>>>(xw, Wh, h0, c0, bv,
                                                   Wa1, ba1, Wa2, ba2, Wc1, bc1, Wc2, bc2,
                                                   lstd, out);
}